// Round 16
// baseline (1312.079 us; speedup 1.0000x reference)
//
#include <hip/hip_runtime.h>

#define B_   4
#define TT_  2048
#define C_   2048
#define H_   32
#define S_   64
#define DF_  7168
#define TCH  512
#define NCH  4

typedef unsigned short u16;
typedef __bf16 bf16x8 __attribute__((ext_vector_type(8)));
typedef float  f32x4  __attribute__((ext_vector_type(4)));

__device__ __forceinline__ u16 f2bf(float f) {
  unsigned u = __builtin_bit_cast(unsigned, f);
  u = u + 0x7FFFu + ((u >> 16) & 1u);
  return (u16)(u >> 16);
}
__device__ __forceinline__ float bf2f(u16 v) {
  unsigned u = ((unsigned)v) << 16;
  return __builtin_bit_cast(float, u);
}

#define GLOAD16(g, l) __builtin_amdgcn_global_load_lds( \
    (const __attribute__((address_space(1))) void*)(g), \
    (__attribute__((address_space(3))) void*)(l), 16, 0, 0)

__device__ __forceinline__ void vmcnt2() { asm volatile("s_waitcnt vmcnt(2)" ::: "memory"); }
__device__ __forceinline__ void vmcnt0() { asm volatile("s_waitcnt vmcnt(0)" ::: "memory"); }

// ---- weight convert+transpose ----------------------------------------------
__global__ __launch_bounds__(256) void wcvt_t(const float* __restrict__ W,
                                              u16* __restrict__ Wt, int K, int Nfull,
                                              int n0off) {
  __shared__ alignas(16) float tile[32][33];
  int nloc = blockIdx.x * 32, k0 = blockIdx.y * 32;
  int tx = threadIdx.x & 31, ty = threadIdx.x >> 5;
  for (int r = ty; r < 32; r += 8)
    tile[r][tx] = W[(size_t)(k0 + r) * Nfull + n0off + nloc + tx];
  __syncthreads();
  for (int r = ty; r < 32; r += 8)
    Wt[(size_t)(nloc + r) * K + k0 + tx] = f2bf(tile[tx][r]);
}

// ---- layernorm over C=2048, f32 in -> bf16 out ------------------------------
__global__ __launch_bounds__(256) void ln_rows(const float* __restrict__ x,
                                               const float* __restrict__ g,
                                               const float* __restrict__ b,
                                               u16* __restrict__ out) {
  const int row = blockIdx.x;
  const float* xr = x + (size_t)row * C_;
  float v[8]; float s = 0.f, s2 = 0.f;
#pragma unroll
  for (int i = 0; i < 8; i++) { v[i] = xr[threadIdx.x + i * 256]; s += v[i]; s2 += v[i] * v[i]; }
#pragma unroll
  for (int o = 32; o > 0; o >>= 1) { s += __shfl_down(s, o); s2 += __shfl_down(s2, o); }
  __shared__ float rs[4], rs2[4];
  int wid = threadIdx.x >> 6, lane = threadIdx.x & 63;
  if (lane == 0) { rs[wid] = s; rs2[wid] = s2; }
  __syncthreads();
  s = rs[0] + rs[1] + rs[2] + rs[3];
  s2 = rs2[0] + rs2[1] + rs2[2] + rs2[3];
  float m = s * (1.f / C_);
  float var = s2 * (1.f / C_) - m * m;
  float inv = rsqrtf(var + 1e-5f);
  u16* orow = out + (size_t)row * C_;
#pragma unroll
  for (int i = 0; i < 8; i++) {
    int c = threadIdx.x + i * 256;
    orow[c] = f2bf((v[i] - m) * inv * g[c] + b[c]);
  }
}

// ---- decay tables -----------------------------------------------------------
__global__ void wtabs_k(const float* __restrict__ td, float* __restrict__ wb_tab,
                        float* __restrict__ wk_tab, float* __restrict__ wspow) {
  int h = blockIdx.x, t = threadIdx.x;
  float w = expf(-expf(td[h]));
  wb_tab[h * TCH + t] = powf(w, (float)t);
  wk_tab[h * TCH + t] = powf(w, (float)(TCH - 1 - t));
  if (t == 0) wspow[h] = powf(w, (float)TCH);
}

// ---- time-shift mixes -------------------------------------------------------
__device__ __forceinline__ void mix_body(const u16* cur, const u16* prev, bool hasp,
                                         const float* mc, u16* dst) {
  ushort4 c0 = *(const ushort4*)cur;
  ushort4 c1 = *(const ushort4*)(cur + 4);
  ushort4 p0 = {0, 0, 0, 0}, p1 = {0, 0, 0, 0};
  if (hasp) { p0 = *(const ushort4*)prev; p1 = *(const ushort4*)(prev + 4); }
  float4 mA = *(const float4*)mc;
  float4 mB = *(const float4*)(mc + 4);
  ushort4 r0, r1;
  r0.x = f2bf(bf2f(c0.x) * mA.x + bf2f(p0.x) * (1.f - mA.x));
  r0.y = f2bf(bf2f(c0.y) * mA.y + bf2f(p0.y) * (1.f - mA.y));
  r0.z = f2bf(bf2f(c0.z) * mA.z + bf2f(p0.z) * (1.f - mA.z));
  r0.w = f2bf(bf2f(c0.w) * mA.w + bf2f(p0.w) * (1.f - mA.w));
  r1.x = f2bf(bf2f(c1.x) * mB.x + bf2f(p1.x) * (1.f - mB.x));
  r1.y = f2bf(bf2f(c1.y) * mB.y + bf2f(p1.y) * (1.f - mB.y));
  r1.z = f2bf(bf2f(c1.z) * mB.z + bf2f(p1.z) * (1.f - mB.z));
  r1.w = f2bf(bf2f(c1.w) * mB.w + bf2f(p1.w) * (1.f - mB.w));
  *(ushort4*)dst = r0;
  *(ushort4*)(dst + 4) = r1;
}

__global__ __launch_bounds__(256) void mix3(const u16* __restrict__ h,
                                            const float* __restrict__ mk,
                                            const float* __restrict__ mv,
                                            const float* __restrict__ mr,
                                            u16* __restrict__ xk, u16* __restrict__ xv,
                                            u16* __restrict__ xr) {
  size_t i8 = (size_t)blockIdx.x * 256 + threadIdx.x;
  size_t off = i8 * 8;
  int c0 = (int)(off & (C_ - 1));
  int row = (int)(i8 >> 8);
  bool hasp = (row & (TT_ - 1)) != 0;
  const u16* cur = h + off;
  const u16* prev = cur - C_;
  mix_body(cur, prev, hasp, mk + c0, xk + off);
  mix_body(cur, prev, hasp, mv + c0, xv + off);
  mix_body(cur, prev, hasp, mr + c0, xr + off);
}

__global__ __launch_bounds__(256) void mix2(const u16* __restrict__ h,
                                            const float* __restrict__ mk,
                                            const float* __restrict__ mr,
                                            u16* __restrict__ xk, u16* __restrict__ xr) {
  size_t i8 = (size_t)blockIdx.x * 256 + threadIdx.x;
  size_t off = i8 * 8;
  int c0 = (int)(off & (C_ - 1));
  int row = (int)(i8 >> 8);
  bool hasp = (row & (TT_ - 1)) != 0;
  const u16* cur = h + off;
  const u16* prev = cur - C_;
  mix_body(cur, prev, hasp, mk + c0, xk + off);
  mix_body(cur, prev, hasp, mr + c0, xr + off);
}

// ---- GEMM v5 (gemm4): BM=256, BN=256, BK=64, 512 thr / 8 waves (2M x 4N),
// wave tile 128x64 (acc[8][4]). 2 double-buffers (128 KB LDS). 4 phases/K-tile.
// Staging order of tile t+1 across t's phases: (B0,B1),(B2,B3),(A0,A2),(A1,A3);
// vmcnt(2) each phase end leaves exactly {A1',A3'}, drained by t+1 p1-end wait
// before t+1 p2 reads them (validated round 14).
// EPI: 0 = bf16 store ; 1 = f32 out = acc + res ; 2 = bf16 relu(acc)^2 ;
//      3 = bf16 sigmoid ; 9 = f32 out = out + bf16(sr)*acc
template <int EPI>
__global__ __launch_bounds__(512) void gemm4(const u16* __restrict__ A,
                                             const u16* __restrict__ Bt,
                                             void* __restrict__ Cv,
                                             const float* __restrict__ res,
                                             const u16* __restrict__ srp,
                                             int N, int K, int lda, int ldb, int gy) {
  __shared__ alignas(16) u16 As[2][256 * 64];
  __shared__ alignas(16) u16 Bs[2][256 * 64];
  const int nwg = gridDim.x, qq = nwg >> 3;
  const int wg = (int)(blockIdx.x & 7) * qq + (int)(blockIdx.x >> 3);
  const int bx = wg / gy, by = wg % gy;
  const int tid = threadIdx.x, w = tid >> 6, lane = tid & 63;
  const int fr = lane & 15, fq = lane >> 4;
  const int m0 = bx * 256, n0 = by * 256;
  const int wm = (w >> 2) * 128;
  const int wn = (w & 3) * 64;
  const int rowS = tid >> 3;
  const int colS = ((tid & 7) * 8) ^ ((rowS & 7) << 3);  // T2 inverse-swizzled source
  const u16* Ag = A + (size_t)(m0 + rowS) * lda + colS;
  const u16* Bg = Bt + (size_t)(n0 + rowS) * ldb + colS;
  const int NT = K >> 6;

  f32x4 acc[8][4];
#pragma unroll
  for (int m = 0; m < 8; m++)
#pragma unroll
    for (int n = 0; n < 4; n++) acc[m][n] = (f32x4){0.f, 0.f, 0.f, 0.f};

#define STG_A4(p, k0, j) GLOAD16(Ag + (size_t)((j) * 64) * lda + (k0), \
    (char*)As[p] + (j) * 8192 + w * 1024)
#define STG_B4(p, k0, j) GLOAD16(Bg + (size_t)((j) * 64) * ldb + (k0), \
    (char*)Bs[p] + (j) * 8192 + w * 1024)
#define RD_A4(p, kk, r) (*(const bf16x8*)((char*)As[p] + \
    ((((r) * 128) + (kk) * 64 + fq * 16) ^ (((r) & 7) << 4))))
#define RD_B4(p, kk, r) (*(const bf16x8*)((char*)Bs[p] + \
    ((((r) * 128) + (kk) * 64 + fq * 16) ^ (((r) & 7) << 4))))

  // prologue: stage tile 0; issue A1,A3 LAST so vmcnt(2) leaves exactly them
  STG_B4(0, 0, 0); STG_B4(0, 0, 1); STG_B4(0, 0, 2); STG_B4(0, 0, 3);
  STG_A4(0, 0, 0); STG_A4(0, 0, 2); STG_A4(0, 0, 1); STG_A4(0, 0, 3);
  vmcnt2();
  __builtin_amdgcn_s_barrier();

  for (int t = 0; t < NT; t++) {
    const int p = t & 1;
    const bool st = (t + 1) < NT;
    const int k1 = (t + 1) << 6;
    bf16x8 av[4], bv[4];

    // ---- phase 1: kk0, M-half0 (reads A0/A2 + B stages) ----
#pragma unroll
    for (int i = 0; i < 4; i++) av[i] = RD_A4(p, 0, wm + i * 16 + fr);
#pragma unroll
    for (int n = 0; n < 4; n++) bv[n] = RD_B4(p, 0, wn + n * 16 + fr);
    if (st) { STG_B4(p ^ 1, k1, 0); STG_B4(p ^ 1, k1, 1); vmcnt2(); } else vmcnt0();
    __builtin_amdgcn_s_barrier();
    __builtin_amdgcn_s_setprio(1);
#pragma unroll
    for (int i = 0; i < 4; i++)
#pragma unroll
      for (int n = 0; n < 4; n++)
        acc[i][n] = __builtin_amdgcn_mfma_f32_16x16x32_bf16(av[i], bv[n], acc[i][n], 0, 0, 0);
    __builtin_amdgcn_s_setprio(0);
    __builtin_amdgcn_s_barrier();

    // ---- phase 2: kk0, M-half1 (reads A1/A3; reuse bv) ----
#pragma unroll
    for (int i = 0; i < 4; i++) av[i] = RD_A4(p, 0, wm + 64 + i * 16 + fr);
    if (st) { STG_B4(p ^ 1, k1, 2); STG_B4(p ^ 1, k1, 3); vmcnt2(); }
    __builtin_amdgcn_s_barrier();
    __builtin_amdgcn_s_setprio(1);
#pragma unroll
    for (int i = 0; i < 4; i++)
#pragma unroll
      for (int n = 0; n < 4; n++)
        acc[4 + i][n] = __builtin_amdgcn_mfma_f32_16x16x32_bf16(av[i], bv[n], acc[4 + i][n], 0, 0, 0);
    __builtin_amdgcn_s_setprio(0);
    __builtin_amdgcn_s_barrier();

    // ---- phase 3: kk1, M-half0 ----
#pragma unroll
    for (int i = 0; i < 4; i++) av[i] = RD_A4(p, 1, wm + i * 16 + fr);
#pragma unroll
    for (int n = 0; n < 4; n++) bv[n] = RD_B4(p, 1, wn + n * 16 + fr);
    if (st) { STG_A4(p ^ 1, k1, 0); STG_A4(p ^ 1, k1, 2); vmcnt2(); }
    __builtin_amdgcn_s_barrier();
    __builtin_amdgcn_s_setprio(1);
#pragma unroll
    for (int i = 0; i < 4; i++)
#pragma unroll
      for (int n = 0; n < 4; n++)
        acc[i][n] = __builtin_amdgcn_mfma_f32_16x16x32_bf16(av[i], bv[n], acc[i][n], 0, 0, 0);
    __builtin_amdgcn_s_setprio(0);
    __builtin_amdgcn_s_barrier();

    // ---- phase 4: kk1, M-half1 (reuse bv) ----
#pragma unroll
    for (int i = 0; i < 4; i++) av[i] = RD_A4(p, 1, wm + 64 + i * 16 + fr);
    if (st) { STG_A4(p ^ 1, k1, 1); STG_A4(p ^ 1, k1, 3); vmcnt2(); }
    __builtin_amdgcn_s_barrier();
    __builtin_amdgcn_s_setprio(1);
#pragma unroll
    for (int i = 0; i < 4; i++)
#pragma unroll
      for (int n = 0; n < 4; n++)
        acc[4 + i][n] = __builtin_amdgcn_mfma_f32_16x16x32_bf16(av[i], bv[n], acc[4 + i][n], 0, 0, 0);
    __builtin_amdgcn_s_setprio(0);
    __builtin_amdgcn_s_barrier();
  }
#undef STG_A4
#undef STG_B4
#undef RD_A4
#undef RD_B4

#pragma unroll
  for (int m = 0; m < 8; m++)
#pragma unroll
    for (int n = 0; n < 4; n++)
#pragma unroll
      for (int j = 0; j < 4; j++) {
        int row = m0 + wm + m * 16 + fq * 4 + j;
        int col = n0 + wn + n * 16 + fr;
        size_t idx = (size_t)row * N + col;
        float v = acc[m][n][j];
        if (EPI == 0) ((u16*)Cv)[idx] = f2bf(v);
        else if (EPI == 1) ((float*)Cv)[idx] = v + res[idx];
        else if (EPI == 2) { float r = v > 0.f ? v : 0.f; ((u16*)Cv)[idx] = f2bf(r * r); }
        else if (EPI == 3) ((u16*)Cv)[idx] = f2bf(1.f / (1.f + expf(-v)));
        else {
          float pvv = ((float*)Cv)[idx];
          ((float*)Cv)[idx] = pvv + bf2f(srp[idx]) * v;
        }
      }
}

// ---- kvsum: per-chunk S_c[s][sv] = sum_t wk[t]*K[t][s]*V[t][sv]  (MFMA) -----
__global__ __launch_bounds__(256) void kvsum_m(const u16* __restrict__ K,
                                               const u16* __restrict__ V,
                                               const float* __restrict__ wk_tab,
                                               float* __restrict__ SC) {
  const int bh = blockIdx.x & 127, c = blockIdx.x >> 7;
  const int b = bh >> 5, h = bh & 31;
  const int tid = threadIdx.x, w = tid >> 6, lane = tid & 63;
  const int fr = lane & 15, fq = lane >> 4;
  const size_t chunkbase = (size_t)b * TT_ + (size_t)c * TCH;
  const u16* Kp = K + chunkbase * C_ + h * 64;
  const u16* Vp = V + chunkbase * C_ + h * 64;
  __shared__ alignas(16) u16 Kts[64 * 128];
  __shared__ alignas(16) u16 Vts[64 * 128];
  f32x4 acc[4];
#pragma unroll
  for (int n = 0; n < 4; n++) acc[n] = (f32x4){0.f, 0.f, 0.f, 0.f};

  for (int tb = 0; tb < 4; tb++) {
    __syncthreads();
    const int u = tid >> 1;
    const int tg = tb * 128 + u;
    const float wkv = wk_tab[h * TCH + tg];
#pragma unroll
    for (int i = 0; i < 4; i++) {
      int s0 = (tid & 1) * 32 + i * 8;
      uint4 dK = *(const uint4*)(Kp + (size_t)tg * C_ + s0);
      uint4 dV = *(const uint4*)(Vp + (size_t)tg * C_ + s0);
      const u16* ek = (const u16*)&dK;
      const u16* ev = (const u16*)&dV;
#pragma unroll
      for (int j = 0; j < 8; j++) {
        int s = s0 + j;
        int byte = s * 256 + u * 2;
        byte ^= (s & 7) << 4;
        *(u16*)((char*)Kts + byte) = f2bf(bf2f(ek[j]) * wkv);
        *(u16*)((char*)Vts + byte) = ev[j];
      }
    }
    __syncthreads();
#pragma unroll
    for (int kk = 0; kk < 4; kk++) {
      int rbyteA = (w * 16 + fr) * 256 + kk * 64 + fq * 16;
      rbyteA ^= (fr & 7) << 4;
      bf16x8 av = *(const bf16x8*)((char*)Kts + rbyteA);
#pragma unroll
      for (int n = 0; n < 4; n++) {
        int rbyteB = (n * 16 + fr) * 256 + kk * 64 + fq * 16;
        rbyteB ^= (fr & 7) << 4;
        bf16x8 bv = *(const bf16x8*)((char*)Vts + rbyteB);
        acc[n] = __builtin_amdgcn_mfma_f32_16x16x32_bf16(av, bv, acc[n], 0, 0, 0);
      }
    }
  }
  float* out = SC + ((size_t)c * 128 + bh) * 4096;
#pragma unroll
  for (int n = 0; n < 4; n++)
#pragma unroll
    for (int j = 0; j < 4; j++) {
      int srow = w * 16 + fq * 4 + j;
      int scol = n * 16 + fr;
      out[srow * 64 + scol] = acc[n][j];
    }
}

// ---- state combine: STt[c][s][sp] = bf16( sum_{j<c} ws^(c-1-j) SC[j][sp][s] )
__global__ __launch_bounds__(256) void stcomb(const float* __restrict__ SC,
                                              u16* __restrict__ STt,
                                              const float* __restrict__ wspow) {
  const int bh = blockIdx.x;
  const float ws = wspow[bh & 31];
  const int tid = threadIdx.x;
#pragma unroll
  for (int e = 0; e < 16; e++) {
    int idxT = e * 256 + tid;
    int s = idxT >> 6, sp = idxT & 63;
    int src = sp * 64 + s;
    float st = 0.f;
#pragma unroll
    for (int c = 0; c < 4; c++) {
      STt[((size_t)c * 128 + bh) * 4096 + idxT] = f2bf(st);
      st = ws * st + SC[((size_t)c * 128 + bh) * 4096 + src];
    }
  }
}

// ---- attention output (MFMA, batched over chunks; 34KB LDS) -----------------
__global__ __launch_bounds__(256) void att_out_m(const u16* __restrict__ R,
                                                 const u16* __restrict__ K,
                                                 const u16* __restrict__ V,
                                                 const u16* __restrict__ STt,
                                                 const float* __restrict__ wb_tab,
                                                 const float* __restrict__ u_vec,
                                                 u16* __restrict__ xa) {
  const int bh = blockIdx.x;
  const int ti = blockIdx.y;
  const int c  = blockIdx.z;
  const int b = bh >> 5, h = bh & 31;
  const int tid = threadIdx.x, w = tid >> 6, lane = tid & 63;
  const int fr = lane & 15, fq = lane >> 4;
  const int t0 = ti * 64;
  const size_t chunkbase = (size_t)b * TT_ + (size_t)c * TCH;
  const u16* Rp = R + (chunkbase + t0) * C_ + h * 64;
  const u16* Kp = K + chunkbase * C_ + h * 64;
  const u16* Vp = V + chunkbase * C_ + h * 64;

  __shared__ alignas(16) u16 Rs[64 * 64];
  __shared__ alignas(16) u16 Ks[64 * 64];
  __shared__ alignas(16) u16 Vts[64 * 64];
  __shared__ alignas(16) u16 Xs[64 * 64];
  __shared__ float wbs[512];

#pragma unroll
  for (int it = 0; it < 2; it++) {
    int r = (tid >> 3) + it * 32;
    int cb = (tid & 7) * 16;
    uint4 d = *(const uint4*)((const char*)(Rp + (size_t)r * C_) + cb);
    int byte = (r * 128 + cb) ^ ((r & 7) << 4);
    *(uint4*)((char*)Rs + byte) = d;
  }
  const u16* stg = STt + ((size_t)c * 128 + bh) * 4096;
#pragma unroll
  for (int it = 0; it < 2; it++) {
    int s = (tid >> 3) + it * 32;
    int cb = (tid & 7) * 16;
    uint4 d = *(const uint4*)((const char*)(stg + (size_t)s * 64) + cb);
    int byte = (s * 128 + cb) ^ ((s & 7) << 4);
    *(uint4*)((char*)Xs + byte) = d;
  }
  wbs[tid] = wb_tab[h * TCH + tid];
  wbs[tid + 256] = wb_tab[h * TCH + tid + 256];
  const float uh = u_vec[h];
  __syncthreads();

  f32x4 pv[4];
#pragma unroll
  for (int n = 0; n < 4; n++) pv[n] = (f32x4){0.f, 0.f, 0.f, 0.f};
#pragma unroll
  for (int kk = 0; kk < 2; kk++) {
    int rbA = ((w * 16 + fr) * 128 + kk * 64 + fq * 16) ^ ((fr & 7) << 4);
    bf16x8 av = *(const bf16x8*)((char*)Rs + rbA);
#pragma unroll
    for (int n = 0; n < 4; n++) {
      int rbB = ((n * 16 + fr) * 128 + kk * 64 + fq * 16) ^ ((fr & 7) << 4);
      bf16x8 bv = *(const bf16x8*)((char*)Xs + rbB);
      pv[n] = __builtin_amdgcn_mfma_f32_16x16x32_bf16(av, bv, pv[n], 0, 0, 0);
    }
  }
#pragma unroll
  for (int n = 0; n < 4; n++)
#pragma unroll
    for (int j = 0; j < 4; j++) {
      int tg = t0 + w * 16 + fq * 4 + j;
      pv[n][j] *= wbs[tg];
    }

  for (int ub = 0; ub <= ti; ub++) {
    const int u0 = ub * 64;
    __syncthreads();
#pragma unroll
    for (int it = 0; it < 2; it++) {
      int r = (tid >> 3) + it * 32;
      int cb = (tid & 7) * 16;
      uint4 d = *(const uint4*)((const char*)(Kp + (size_t)(u0 + r) * C_) + cb);
      int byte = (r * 128 + cb) ^ ((r & 7) << 4);
      *(uint4*)((char*)Ks + byte) = d;
    }
#pragma unroll
    for (int it = 0; it < 2; it++) {
      int u = (tid >> 3) + it * 32;
      int s0 = (tid & 7) * 8;
      uint4 d = *(const uint4*)(Vp + (size_t)(u0 + u) * C_ + s0);
      const u16* ev = (const u16*)&d;
#pragma unroll
      for (int j = 0; j < 8; j++) {
        int s = s0 + j;
        int byte = (s * 128 + u * 2) ^ ((s & 7) << 4);
        *(u16*)((char*)Vts + byte) = ev[j];
      }
    }
    __syncthreads();
    f32x4 accA[4];
#pragma unroll
    for (int n = 0; n < 4; n++) accA[n] = (f32x4){0.f, 0.f, 0.f, 0.f};
#pragma unroll
    for (int kk = 0; kk < 2; kk++) {
      int rbA = ((w * 16 + fr) * 128 + kk * 64 + fq * 16) ^ ((fr & 7) << 4);
      bf16x8 av = *(const bf16x8*)((char*)Rs + rbA);
#pragma unroll
      for (int n = 0; n < 4; n++) {
        int rbB = ((n * 16 + fr) * 128 + kk * 64 + fq * 16) ^ ((fr & 7) << 4);
        bf16x8 bv = *(const bf16x8*)((char*)Ks + rbB);
        accA[n] = __builtin_amdgcn_mfma_f32_16x16x32_bf16(av, bv, accA[n], 0, 0, 0);
      }
    }
#pragma unroll
    for (int n = 0; n < 4; n++) {
#pragma unroll
      for (int j = 0; j < 4; j++) {
        int tl = w * 16 + fq * 4 + j;
        int tg = t0 + tl;
        int u = u0 + n * 16 + fr;
        int d = tg - u;
        float f = (d > 0) ? wbs[d - 1] : ((d == 0) ? uh : 0.f);
        int byte = (tl * 128 + (n * 16 + fr) * 2) ^ ((tl & 7) << 4);
        *(u16*)((char*)Xs + byte) = f2bf(accA[n][j] * f);
      }
    }
#pragma unroll
    for (int kk = 0; kk < 2; kk++) {
      int rbA = ((w * 16 + fr) * 128 + kk * 64 + fq * 16) ^ ((fr & 7) << 4);
      bf16x8 ap = *(const bf16x8*)((char*)Xs + rbA);
#pragma unroll
      for (int n = 0; n < 4; n++) {
        int rbB = ((n * 16 + fr) * 128 + kk * 64 + fq * 16) ^ ((fr & 7) << 4);
        bf16x8 vp = *(const bf16x8*)((char*)Vts + rbB);
        pv[n] = __builtin_amdgcn_mfma_f32_16x16x32_bf16(ap, vp, pv[n], 0, 0, 0);
      }
    }
  }
  u16* xout = xa + (chunkbase + t0) * C_ + h * 64;
#pragma unroll
  for (int n = 0; n < 4; n++)
#pragma unroll
    for (int j = 0; j < 4; j++) {
      int tl = w * 16 + fq * 4 + j;
      xout[(size_t)tl * C_ + n * 16 + fr] = f2bf(pv[n][j]);
    }
}

// ---- per-head groupnorm ------------------------------------------------------
__global__ __launch_bounds__(256) void gnorm(const u16* __restrict__ xa,
                                             const float* __restrict__ g,
                                             const float* __restrict__ b,
                                             u16* __restrict__ out) {
  const int row = blockIdx.x;
  const int lane = threadIdx.x & 63, wv = threadIdx.x >> 6;
  const u16* xp = xa + (size_t)row * C_;
  u16* op = out + (size_t)row * C_;
  for (int h = wv; h < 32; h += 4) {
    float v = bf2f(xp[h * 64 + lane]) * 0.125f;
    float s = v, s2 = v * v;
#pragma unroll
    for (int o = 32; o > 0; o >>= 1) { s += __shfl_down(s, o); s2 += __shfl_down(s2, o); }
    s = __shfl(s, 0); s2 = __shfl(s2, 0);
    float m = s * (1.f / 64.f), var = s2 * (1.f / 64.f) - m * m;
    float nv = (v - m) * rsqrtf(var + 1e-5f);
    op[h * 64 + lane] = f2bf(nv * g[h * 64 + lane] + b[h * 64 + lane]);
  }
}

// ---- launcher ---------------------------------------------------------------
extern "C" void kernel_launch(void* const* d_in, const int* in_sizes, int n_in,
                              void* d_out, int out_size, void* d_ws, size_t ws_size,
                              hipStream_t stream) {
  (void)in_sizes; (void)n_in; (void)out_size; (void)ws_size;
  const float* x    = (const float*)d_in[0];
  const float* ln1g = (const float*)d_in[1];
  const float* ln1b = (const float*)d_in[2];
  const float* ln2g = (const float*)d_in[3];
  const float* ln2b = (const float*)d_in[4];
  const float* amk  = (const float*)d_in[5];
  const float* amv  = (const float*)d_in[6];
  const float* amr  = (const float*)d_in[7];
  const float* tdec = (const float*)d_in[8];
  const float* tfaa = (const float*)d_in[9];
  const float* Wr   = (const float*)d_in[10];
  const float* Wk   = (const float*)d_in[11];
  const float* Wv   = (const float*)d_in[12];
  const float* Wo   = (const float*)d_in[13];
  const float* lnxg = (const float*)d_in[14];
  const float* lnxb = (const float*)d_in[15];
  const float* fmk  = (const float*)d_in[16];
  const float* fmr  = (const float*)d_in[17];
  const float* Wfk  = (const float*)d_in[18];
  const float* Wfr  = (const float*)d_in[19];
  const float* Wfv  = (const float*)d_in[20];

  char* ws = (char*)d_ws;
  const size_t MB = 1ull << 20;
  u16* WR  = (u16*)(ws + 0 * MB);
  u16* WK  = (u16*)(ws + 8 * MB);
  u16* WV  = (u16*)(ws + 16 * MB);
  u16* WO  = (u16*)(ws + 24 * MB);
  u16* WFR = (u16*)(ws + 32 * MB);
  u16* WFK = (u16*)(ws + 40 * MB);
  u16* WFV = (u16*)(ws + 68 * MB);
  u16* H1  = (u16*)(ws + 96 * MB);
  u16* XR  = (u16*)(ws + 128 * MB);
  u16* XK  = (u16*)(ws + 160 * MB);
  u16* XV  = (u16*)(ws + 192 * MB);
  float* WBT = (float*)(ws + 224 * MB);
  float* WKT = (float*)(ws + 224 * MB + 65536);
  float* WSP = (float*)(ws + 224 * MB + 131072);
  float* SCb = (float*)(ws + 0 * MB);
  u16* STTb  = (u16*)(ws + 8 * MB);
  u16* RB   = H1;
  u16* KB   = XR;
  u16* VB   = XK;
  u16* XA   = XV;
  u16* XAN  = H1;
  u16* H2   = XV;
  u16* XK2  = WR;
  u16* XR2  = H1;
  u16* SR   = XR;
  u16* KFH  = XK;                    // (8192, 3584) bf16 N-half = 56 MB (160-216)
  float* OUT = (float*)d_out;

  dim3 blk(256), gblk(512);
  wcvt_t<<<dim3(64, 64), blk, 0, stream>>>(Wr, WR, 2048, 2048, 0);
  wcvt_t<<<dim3(64, 64), blk, 0, stream>>>(Wk, WK, 2048, 2048, 0);
  wcvt_t<<<dim3(64, 64), blk, 0, stream>>>(Wv, WV, 2048, 2048, 0);
  wcvt_t<<<dim3(64, 64), blk, 0, stream>>>(Wo, WO, 2048, 2048, 0);
  wcvt_t<<<dim3(64, 64), blk, 0, stream>>>(Wfr, WFR, 2048, 2048, 0);
  wcvt_t<<<dim3(224, 64), blk, 0, stream>>>(Wfk, WFK, 2048, 7168, 0);
  wcvt_t<<<dim3(64, 224), blk, 0, stream>>>(Wfv, WFV, 7168, 2048, 0);

  // ---- attention branch ----
  ln_rows<<<8192, blk, 0, stream>>>(x, ln1g, ln1b, H1);
  mix3<<<8192, blk, 0, stream>>>(H1, amk, amv, amr, XK, XV, XR);
  gemm4<0><<<256, gblk, 0, stream>>>(XR, WR, RB, nullptr, nullptr, 2048, 2048, 2048, 2048, 8);
  gemm4<0><<<256, gblk, 0, stream>>>(XK, WK, KB, nullptr, nullptr, 2048, 2048, 2048, 2048, 8);
  gemm4<0><<<256, gblk, 0, stream>>>(XV, WV, VB, nullptr, nullptr, 2048, 2048, 2048, 2048, 8);

  wtabs_k<<<32, 512, 0, stream>>>(tdec, WBT, WKT, WSP);
  kvsum_m<<<512, blk, 0, stream>>>(KB, VB, WKT, SCb);
  stcomb<<<128, blk, 0, stream>>>(SCb, STTb, WSP);
  att_out_m<<<dim3(128, 8, 4), blk, 0, stream>>>(RB, KB, VB, STTb, WBT, tfaa, XA);

  gnorm<<<8192, blk, 0, stream>>>(XA, lnxg, lnxb, XAN);
  gemm4<1><<<256, gblk, 0, stream>>>(XAN, WO, OUT, x, nullptr, 2048, 2048, 2048, 2048, 8);

  // ---- FFN branch (N-split: kf half = cols [h*3584, h*3584+3584) of kf) ----
  ln_rows<<<8192, blk, 0, stream>>>(OUT, ln2g, ln2b, H2);
  mix2<<<8192, blk, 0, stream>>>(H2, fmk, fmr, XK2, XR2);
  gemm4<3><<<256, gblk, 0, stream>>>(XR2, WFR, SR, nullptr, nullptr, 2048, 2048, 2048, 2048, 8);

  for (int half = 0; half < 2; half++) {
    // kf N-half: KFH (8192, 3584) = relu(xk2 @ Wfk[:, half])^2
    const u16* wfk_h = WFK + (size_t)half * 3584 * 2048;  // WFKT rows (= kf cols)
    gemm4<2><<<448, gblk, 0, stream>>>(XK2, wfk_h, KFH, nullptr, nullptr,
                                       3584, 2048, 2048, 2048, 14);
    // kv K-half: OUT += sr * (KFH @ Wfv[half-rows]); WFVT col-offset = K-slice
    const u16* wfv_h = WFV + (size_t)half * 3584;
    gemm4<9><<<256, gblk, 0, stream>>>(KFH, wfv_h, OUT, nullptr, SR,
                                       2048, 3584, 3584, 7168, 8);
  }
}

// Round 17
// 1251.207 us; speedup vs baseline: 1.0487x; 1.0487x over previous
//
#include <hip/hip_runtime.h>

#define B_   4
#define TT_  2048
#define C_   2048
#define H_   32
#define S_   64
#define DF_  7168
#define TCH  512
#define NCH  4

typedef unsigned short u16;
typedef __bf16 bf16x8 __attribute__((ext_vector_type(8)));
typedef float  f32x4  __attribute__((ext_vector_type(4)));

__device__ __forceinline__ u16 f2bf(float f) {
  unsigned u = __builtin_bit_cast(unsigned, f);
  u = u + 0x7FFFu + ((u >> 16) & 1u);
  return (u16)(u >> 16);
}
__device__ __forceinline__ float bf2f(u16 v) {
  unsigned u = ((unsigned)v) << 16;
  return __builtin_bit_cast(float, u);
}

#define GLOAD16(g, l) __builtin_amdgcn_global_load_lds( \
    (const __attribute__((address_space(1))) void*)(g), \
    (__attribute__((address_space(3))) void*)(l), 16, 0, 0)

__device__ __forceinline__ void vmcnt6() { asm volatile("s_waitcnt vmcnt(6)" ::: "memory"); }
__device__ __forceinline__ void vmcnt2() { asm volatile("s_waitcnt vmcnt(2)" ::: "memory"); }
__device__ __forceinline__ void vmcnt0() { asm volatile("s_waitcnt vmcnt(0)" ::: "memory"); }

// ---- weight convert+transpose ----------------------------------------------
__global__ __launch_bounds__(256) void wcvt_t(const float* __restrict__ W,
                                              u16* __restrict__ Wt, int K, int Nfull,
                                              int n0off) {
  __shared__ alignas(16) float tile[32][33];
  int nloc = blockIdx.x * 32, k0 = blockIdx.y * 32;
  int tx = threadIdx.x & 31, ty = threadIdx.x >> 5;
  for (int r = ty; r < 32; r += 8)
    tile[r][tx] = W[(size_t)(k0 + r) * Nfull + n0off + nloc + tx];
  __syncthreads();
  for (int r = ty; r < 32; r += 8)
    Wt[(size_t)(nloc + r) * K + k0 + tx] = f2bf(tile[tx][r]);
}

// ---- layernorm over C=2048, f32 in -> bf16 out ------------------------------
__global__ __launch_bounds__(256) void ln_rows(const float* __restrict__ x,
                                               const float* __restrict__ g,
                                               const float* __restrict__ b,
                                               u16* __restrict__ out) {
  const int row = blockIdx.x;
  const float* xr = x + (size_t)row * C_;
  float v[8]; float s = 0.f, s2 = 0.f;
#pragma unroll
  for (int i = 0; i < 8; i++) { v[i] = xr[threadIdx.x + i * 256]; s += v[i]; s2 += v[i] * v[i]; }
#pragma unroll
  for (int o = 32; o > 0; o >>= 1) { s += __shfl_down(s, o); s2 += __shfl_down(s2, o); }
  __shared__ float rs[4], rs2[4];
  int wid = threadIdx.x >> 6, lane = threadIdx.x & 63;
  if (lane == 0) { rs[wid] = s; rs2[wid] = s2; }
  __syncthreads();
  s = rs[0] + rs[1] + rs[2] + rs[3];
  s2 = rs2[0] + rs2[1] + rs2[2] + rs2[3];
  float m = s * (1.f / C_);
  float var = s2 * (1.f / C_) - m * m;
  float inv = rsqrtf(var + 1e-5f);
  u16* orow = out + (size_t)row * C_;
#pragma unroll
  for (int i = 0; i < 8; i++) {
    int c = threadIdx.x + i * 256;
    orow[c] = f2bf((v[i] - m) * inv * g[c] + b[c]);
  }
}

// ---- decay tables -----------------------------------------------------------
__global__ void wtabs_k(const float* __restrict__ td, float* __restrict__ wb_tab,
                        float* __restrict__ wk_tab, float* __restrict__ wspow) {
  int h = blockIdx.x, t = threadIdx.x;
  float w = expf(-expf(td[h]));
  wb_tab[h * TCH + t] = powf(w, (float)t);
  wk_tab[h * TCH + t] = powf(w, (float)(TCH - 1 - t));
  if (t == 0) wspow[h] = powf(w, (float)TCH);
}

// ---- time-shift mixes -------------------------------------------------------
__device__ __forceinline__ void mix_body(const u16* cur, const u16* prev, bool hasp,
                                         const float* mc, u16* dst) {
  ushort4 c0 = *(const ushort4*)cur;
  ushort4 c1 = *(const ushort4*)(cur + 4);
  ushort4 p0 = {0, 0, 0, 0}, p1 = {0, 0, 0, 0};
  if (hasp) { p0 = *(const ushort4*)prev; p1 = *(const ushort4*)(prev + 4); }
  float4 mA = *(const float4*)mc;
  float4 mB = *(const float4*)(mc + 4);
  ushort4 r0, r1;
  r0.x = f2bf(bf2f(c0.x) * mA.x + bf2f(p0.x) * (1.f - mA.x));
  r0.y = f2bf(bf2f(c0.y) * mA.y + bf2f(p0.y) * (1.f - mA.y));
  r0.z = f2bf(bf2f(c0.z) * mA.z + bf2f(p0.z) * (1.f - mA.z));
  r0.w = f2bf(bf2f(c0.w) * mA.w + bf2f(p0.w) * (1.f - mA.w));
  r1.x = f2bf(bf2f(c1.x) * mB.x + bf2f(p1.x) * (1.f - mB.x));
  r1.y = f2bf(bf2f(c1.y) * mB.y + bf2f(p1.y) * (1.f - mB.y));
  r1.z = f2bf(bf2f(c1.z) * mB.z + bf2f(p1.z) * (1.f - mB.z));
  r1.w = f2bf(bf2f(c1.w) * mB.w + bf2f(p1.w) * (1.f - mB.w));
  *(ushort4*)dst = r0;
  *(ushort4*)(dst + 4) = r1;
}

__global__ __launch_bounds__(256) void mix3(const u16* __restrict__ h,
                                            const float* __restrict__ mk,
                                            const float* __restrict__ mv,
                                            const float* __restrict__ mr,
                                            u16* __restrict__ xk, u16* __restrict__ xv,
                                            u16* __restrict__ xr) {
  size_t i8 = (size_t)blockIdx.x * 256 + threadIdx.x;
  size_t off = i8 * 8;
  int c0 = (int)(off & (C_ - 1));
  int row = (int)(i8 >> 8);
  bool hasp = (row & (TT_ - 1)) != 0;
  const u16* cur = h + off;
  const u16* prev = cur - C_;
  mix_body(cur, prev, hasp, mk + c0, xk + off);
  mix_body(cur, prev, hasp, mv + c0, xv + off);
  mix_body(cur, prev, hasp, mr + c0, xr + off);
}

__global__ __launch_bounds__(256) void mix2(const u16* __restrict__ h,
                                            const float* __restrict__ mk,
                                            const float* __restrict__ mr,
                                            u16* __restrict__ xk, u16* __restrict__ xr) {
  size_t i8 = (size_t)blockIdx.x * 256 + threadIdx.x;
  size_t off = i8 * 8;
  int c0 = (int)(off & (C_ - 1));
  int row = (int)(i8 >> 8);
  bool hasp = (row & (TT_ - 1)) != 0;
  const u16* cur = h + off;
  const u16* prev = cur - C_;
  mix_body(cur, prev, hasp, mk + c0, xk + off);
  mix_body(cur, prev, hasp, mr + c0, xr + off);
}

// ---- GEMM v5 (gemm4): BM=256, BN=256, BK=64, 512 thr / 8 waves (2M x 4N),
// wave tile 128x64 (acc[8][4]). 2 double-buffers (128 KB LDS). 4 phases/K-tile.
// Staging order (B0,B1),(B2,B3),(A0,A2),(A1,A3); vmcnt(2) per phase end leaves
// exactly {A1',A3'}, drained by t+1 p1-end wait before p2 reads (validated r14).
// EPI: 0 = bf16 store ; 1 = f32 out = acc + res ; 2 = bf16 relu(acc)^2 ; 3 = sigmoid
template <int EPI>
__global__ __launch_bounds__(512) void gemm4(const u16* __restrict__ A,
                                             const u16* __restrict__ Bt,
                                             void* __restrict__ Cv,
                                             const float* __restrict__ res,
                                             int N, int K, int lda, int ldb, int gy) {
  __shared__ alignas(16) u16 As[2][256 * 64];
  __shared__ alignas(16) u16 Bs[2][256 * 64];
  const int nwg = gridDim.x, qq = nwg >> 3;
  const int wg = (int)(blockIdx.x & 7) * qq + (int)(blockIdx.x >> 3);
  const int bx = wg / gy, by = wg % gy;
  const int tid = threadIdx.x, w = tid >> 6, lane = tid & 63;
  const int fr = lane & 15, fq = lane >> 4;
  const int m0 = bx * 256, n0 = by * 256;
  const int wm = (w >> 2) * 128;
  const int wn = (w & 3) * 64;
  const int rowS = tid >> 3;
  const int colS = ((tid & 7) * 8) ^ ((rowS & 7) << 3);
  const u16* Ag = A + (size_t)(m0 + rowS) * lda + colS;
  const u16* Bg = Bt + (size_t)(n0 + rowS) * ldb + colS;
  const int NT = K >> 6;

  f32x4 acc[8][4];
#pragma unroll
  for (int m = 0; m < 8; m++)
#pragma unroll
    for (int n = 0; n < 4; n++) acc[m][n] = (f32x4){0.f, 0.f, 0.f, 0.f};

#define STG_A4(p, k0, j) GLOAD16(Ag + (size_t)((j) * 64) * lda + (k0), \
    (char*)As[p] + (j) * 8192 + w * 1024)
#define STG_B4(p, k0, j) GLOAD16(Bg + (size_t)((j) * 64) * ldb + (k0), \
    (char*)Bs[p] + (j) * 8192 + w * 1024)
#define RD_A4(p, kk, r) (*(const bf16x8*)((char*)As[p] + \
    ((((r) * 128) + (kk) * 64 + fq * 16) ^ (((r) & 7) << 4))))
#define RD_B4(p, kk, r) (*(const bf16x8*)((char*)Bs[p] + \
    ((((r) * 128) + (kk) * 64 + fq * 16) ^ (((r) & 7) << 4))))

  STG_B4(0, 0, 0); STG_B4(0, 0, 1); STG_B4(0, 0, 2); STG_B4(0, 0, 3);
  STG_A4(0, 0, 0); STG_A4(0, 0, 2); STG_A4(0, 0, 1); STG_A4(0, 0, 3);
  vmcnt2();
  __builtin_amdgcn_s_barrier();

  for (int t = 0; t < NT; t++) {
    const int p = t & 1;
    const bool st = (t + 1) < NT;
    const int k1 = (t + 1) << 6;
    bf16x8 av[4], bv[4];

#pragma unroll
    for (int i = 0; i < 4; i++) av[i] = RD_A4(p, 0, wm + i * 16 + fr);
#pragma unroll
    for (int n = 0; n < 4; n++) bv[n] = RD_B4(p, 0, wn + n * 16 + fr);
    if (st) { STG_B4(p ^ 1, k1, 0); STG_B4(p ^ 1, k1, 1); vmcnt2(); } else vmcnt0();
    __builtin_amdgcn_s_barrier();
    __builtin_amdgcn_s_setprio(1);
#pragma unroll
    for (int i = 0; i < 4; i++)
#pragma unroll
      for (int n = 0; n < 4; n++)
        acc[i][n] = __builtin_amdgcn_mfma_f32_16x16x32_bf16(av[i], bv[n], acc[i][n], 0, 0, 0);
    __builtin_amdgcn_s_setprio(0);
    __builtin_amdgcn_s_barrier();

#pragma unroll
    for (int i = 0; i < 4; i++) av[i] = RD_A4(p, 0, wm + 64 + i * 16 + fr);
    if (st) { STG_B4(p ^ 1, k1, 2); STG_B4(p ^ 1, k1, 3); vmcnt2(); }
    __builtin_amdgcn_s_barrier();
    __builtin_amdgcn_s_setprio(1);
#pragma unroll
    for (int i = 0; i < 4; i++)
#pragma unroll
      for (int n = 0; n < 4; n++)
        acc[4 + i][n] = __builtin_amdgcn_mfma_f32_16x16x32_bf16(av[i], bv[n], acc[4 + i][n], 0, 0, 0);
    __builtin_amdgcn_s_setprio(0);
    __builtin_amdgcn_s_barrier();

#pragma unroll
    for (int i = 0; i < 4; i++) av[i] = RD_A4(p, 1, wm + i * 16 + fr);
#pragma unroll
    for (int n = 0; n < 4; n++) bv[n] = RD_B4(p, 1, wn + n * 16 + fr);
    if (st) { STG_A4(p ^ 1, k1, 0); STG_A4(p ^ 1, k1, 2); vmcnt2(); }
    __builtin_amdgcn_s_barrier();
    __builtin_amdgcn_s_setprio(1);
#pragma unroll
    for (int i = 0; i < 4; i++)
#pragma unroll
      for (int n = 0; n < 4; n++)
        acc[i][n] = __builtin_amdgcn_mfma_f32_16x16x32_bf16(av[i], bv[n], acc[i][n], 0, 0, 0);
    __builtin_amdgcn_s_setprio(0);
    __builtin_amdgcn_s_barrier();

#pragma unroll
    for (int i = 0; i < 4; i++) av[i] = RD_A4(p, 1, wm + 64 + i * 16 + fr);
    if (st) { STG_A4(p ^ 1, k1, 1); STG_A4(p ^ 1, k1, 3); vmcnt2(); }
    __builtin_amdgcn_s_barrier();
    __builtin_amdgcn_s_setprio(1);
#pragma unroll
    for (int i = 0; i < 4; i++)
#pragma unroll
      for (int n = 0; n < 4; n++)
        acc[4 + i][n] = __builtin_amdgcn_mfma_f32_16x16x32_bf16(av[i], bv[n], acc[4 + i][n], 0, 0, 0);
    __builtin_amdgcn_s_setprio(0);
    __builtin_amdgcn_s_barrier();
  }
#undef STG_A4
#undef STG_B4
#undef RD_A4
#undef RD_B4

#pragma unroll
  for (int m = 0; m < 8; m++)
#pragma unroll
    for (int n = 0; n < 4; n++)
#pragma unroll
      for (int j = 0; j < 4; j++) {
        int row = m0 + wm + m * 16 + fq * 4 + j;
        int col = n0 + wn + n * 16 + fr;
        size_t idx = (size_t)row * N + col;
        float v = acc[m][n][j];
        if (EPI == 0) ((u16*)Cv)[idx] = f2bf(v);
        else if (EPI == 1) ((float*)Cv)[idx] = v + res[idx];
        else if (EPI == 2) { float r = v > 0.f ? v : 0.f; ((u16*)Cv)[idx] = f2bf(r * r); }
        else ((u16*)Cv)[idx] = f2bf(1.f / (1.f + expf(-v)));
      }
}

// ---- gemm3b: BM=128, BN=256, 3-buffer ring (depth-2), 2 phases x 16 MFMA.
// Same memory schedule as round-12 gemm3 (validated): stage tile t+2 into
// buf[(t+2)%3] (holds tile t-1, dead since previous iteration); single counted
// vmcnt(6) per K-tile at p2-end (leaves t+2's 6 loads in flight). Intra-tile
// reads all come from bufc whose data landed before tile start. Barriers
// halved vs gemm3 (4/tile), 16 MFMA per barrier-pair.
// EPI: 9 = f32 out = out + bf16(sr)*acc
template <int EPI>
__global__ __launch_bounds__(512) void gemm3b(const u16* __restrict__ A,
                                              const u16* __restrict__ Bt,
                                              void* __restrict__ Cv,
                                              const u16* __restrict__ srp,
                                              int N, int K, int lda, int ldb, int gy) {
  __shared__ alignas(16) char smem[3 * 49152];
  const int nwg = gridDim.x, qq = nwg >> 3;
  const int wg = (int)(blockIdx.x & 7) * qq + (int)(blockIdx.x >> 3);
  const int bx = wg / gy, by = wg % gy;
  const int tid = threadIdx.x, w = tid >> 6, lane = tid & 63;
  const int fr = lane & 15, fq = lane >> 4;
  const int m0 = bx * 128, n0 = by * 256;
  const int wm = (w >> 2) * 64, wn = (w & 3) * 64;
  const int rowS = tid >> 3;
  const int colS = ((tid & 7) * 8) ^ ((rowS & 7) << 3);
  const u16* Ag = A + (size_t)(m0 + rowS) * lda + colS;
  const u16* Bg = Bt + (size_t)(n0 + rowS) * ldb + colS;
  const int NT = K >> 6;

  f32x4 acc[4][4];
#pragma unroll
  for (int m = 0; m < 4; m++)
#pragma unroll
    for (int n = 0; n < 4; n++) acc[m][n] = (f32x4){0.f, 0.f, 0.f, 0.f};

#define STG_A(buf, k0, j) GLOAD16(Ag + (size_t)((j) * 64) * lda + (k0), \
    smem + (buf) * 49152 + (j) * 8192 + w * 1024)
#define STG_B(buf, k0, j) GLOAD16(Bg + (size_t)((j) * 64) * ldb + (k0), \
    smem + (buf) * 49152 + 16384 + (j) * 8192 + w * 1024)
#define RD_A(buf, kk, m) (*(const bf16x8*)(smem + (buf) * 49152 + \
    ((((wm + (m) * 16 + fr) * 128) + (kk) * 64 + fq * 16) ^ (((wm + (m) * 16 + fr) & 7) << 4))))
#define RD_B(buf, kk, n) (*(const bf16x8*)(smem + (buf) * 49152 + 16384 + \
    ((((wn + (n) * 16 + fr) * 128) + (kk) * 64 + fq * 16) ^ (((wn + (n) * 16 + fr) & 7) << 4))))

  // prologue: stage tiles 0 and 1 (6 loads each); wait tile 0 only
  STG_A(0, 0, 0); STG_A(0, 0, 1);
  STG_B(0, 0, 0); STG_B(0, 0, 1); STG_B(0, 0, 2); STG_B(0, 0, 3);
  STG_A(1, 64, 0); STG_A(1, 64, 1);
  STG_B(1, 64, 0); STG_B(1, 64, 1); STG_B(1, 64, 2); STG_B(1, 64, 3);
  vmcnt6();
  __builtin_amdgcn_s_barrier();

  int bufc = 0;
  for (int t = 0; t < NT; t++) {
    int b2 = bufc + 2; if (b2 >= 3) b2 -= 3;
    const bool st = (t + 2) < NT;
    const int k2 = (t + 2) << 6;
    bf16x8 av[4], bv[4];

    // ---- phase 1: kk0, all 16 MFMA ----
#pragma unroll
    for (int m = 0; m < 4; m++) av[m] = RD_A(bufc, 0, m);
#pragma unroll
    for (int n = 0; n < 4; n++) bv[n] = RD_B(bufc, 0, n);
    if (st) { STG_A(b2, k2, 0); STG_A(b2, k2, 1); STG_B(b2, k2, 0); }
    __builtin_amdgcn_s_barrier();
    __builtin_amdgcn_s_setprio(1);
#pragma unroll
    for (int m = 0; m < 4; m++)
#pragma unroll
      for (int n = 0; n < 4; n++)
        acc[m][n] = __builtin_amdgcn_mfma_f32_16x16x32_bf16(av[m], bv[n], acc[m][n], 0, 0, 0);
    __builtin_amdgcn_s_setprio(0);
    __builtin_amdgcn_s_barrier();

    // ---- phase 2: kk1, all 16 MFMA ----
#pragma unroll
    for (int m = 0; m < 4; m++) av[m] = RD_A(bufc, 1, m);
#pragma unroll
    for (int n = 0; n < 4; n++) bv[n] = RD_B(bufc, 1, n);
    if (st) { STG_B(b2, k2, 1); STG_B(b2, k2, 2); STG_B(b2, k2, 3); }
    if (st) vmcnt6(); else vmcnt0();   // drain tile t+1's loads; keep t+2's in flight
    __builtin_amdgcn_s_barrier();
    __builtin_amdgcn_s_setprio(1);
#pragma unroll
    for (int m = 0; m < 4; m++)
#pragma unroll
      for (int n = 0; n < 4; n++)
        acc[m][n] = __builtin_amdgcn_mfma_f32_16x16x32_bf16(av[m], bv[n], acc[m][n], 0, 0, 0);
    __builtin_amdgcn_s_setprio(0);
    __builtin_amdgcn_s_barrier();

    bufc = bufc + 1 == 3 ? 0 : bufc + 1;
  }
#undef STG_A
#undef STG_B
#undef RD_A
#undef RD_B

#pragma unroll
  for (int m = 0; m < 4; m++)
#pragma unroll
    for (int n = 0; n < 4; n++)
#pragma unroll
      for (int j = 0; j < 4; j++) {
        int row = m0 + wm + m * 16 + fq * 4 + j;
        int col = n0 + wn + n * 16 + fr;
        size_t idx = (size_t)row * N + col;
        float v = acc[m][n][j];
        if (EPI == 9) {
          float pvv = ((float*)Cv)[idx];
          ((float*)Cv)[idx] = pvv + bf2f(srp[idx]) * v;
        } else {
          ((u16*)Cv)[idx] = f2bf(v);
        }
      }
}

// ---- kvsum: per-chunk S_c[s][sv] = sum_t wk[t]*K[t][s]*V[t][sv]  (MFMA) -----
__global__ __launch_bounds__(256) void kvsum_m(const u16* __restrict__ K,
                                               const u16* __restrict__ V,
                                               const float* __restrict__ wk_tab,
                                               float* __restrict__ SC) {
  const int bh = blockIdx.x & 127, c = blockIdx.x >> 7;
  const int b = bh >> 5, h = bh & 31;
  const int tid = threadIdx.x, w = tid >> 6, lane = tid & 63;
  const int fr = lane & 15, fq = lane >> 4;
  const size_t chunkbase = (size_t)b * TT_ + (size_t)c * TCH;
  const u16* Kp = K + chunkbase * C_ + h * 64;
  const u16* Vp = V + chunkbase * C_ + h * 64;
  __shared__ alignas(16) u16 Kts[64 * 128];
  __shared__ alignas(16) u16 Vts[64 * 128];
  f32x4 acc[4];
#pragma unroll
  for (int n = 0; n < 4; n++) acc[n] = (f32x4){0.f, 0.f, 0.f, 0.f};

  for (int tb = 0; tb < 4; tb++) {
    __syncthreads();
    const int u = tid >> 1;
    const int tg = tb * 128 + u;
    const float wkv = wk_tab[h * TCH + tg];
#pragma unroll
    for (int i = 0; i < 4; i++) {
      int s0 = (tid & 1) * 32 + i * 8;
      uint4 dK = *(const uint4*)(Kp + (size_t)tg * C_ + s0);
      uint4 dV = *(const uint4*)(Vp + (size_t)tg * C_ + s0);
      const u16* ek = (const u16*)&dK;
      const u16* ev = (const u16*)&dV;
#pragma unroll
      for (int j = 0; j < 8; j++) {
        int s = s0 + j;
        int byte = s * 256 + u * 2;
        byte ^= (s & 7) << 4;
        *(u16*)((char*)Kts + byte) = f2bf(bf2f(ek[j]) * wkv);
        *(u16*)((char*)Vts + byte) = ev[j];
      }
    }
    __syncthreads();
#pragma unroll
    for (int kk = 0; kk < 4; kk++) {
      int rbyteA = (w * 16 + fr) * 256 + kk * 64 + fq * 16;
      rbyteA ^= (fr & 7) << 4;
      bf16x8 av = *(const bf16x8*)((char*)Kts + rbyteA);
#pragma unroll
      for (int n = 0; n < 4; n++) {
        int rbyteB = (n * 16 + fr) * 256 + kk * 64 + fq * 16;
        rbyteB ^= (fr & 7) << 4;
        bf16x8 bv = *(const bf16x8*)((char*)Vts + rbyteB);
        acc[n] = __builtin_amdgcn_mfma_f32_16x16x32_bf16(av, bv, acc[n], 0, 0, 0);
      }
    }
  }
  float* out = SC + ((size_t)c * 128 + bh) * 4096;
#pragma unroll
  for (int n = 0; n < 4; n++)
#pragma unroll
    for (int j = 0; j < 4; j++) {
      int srow = w * 16 + fq * 4 + j;
      int scol = n * 16 + fr;
      out[srow * 64 + scol] = acc[n][j];
    }
}

// ---- state combine: STt[c][s][sp] = bf16( sum_{j<c} ws^(c-1-j) SC[j][sp][s] )
__global__ __launch_bounds__(256) void stcomb(const float* __restrict__ SC,
                                              u16* __restrict__ STt,
                                              const float* __restrict__ wspow) {
  const int bh = blockIdx.x;
  const float ws = wspow[bh & 31];
  const int tid = threadIdx.x;
#pragma unroll
  for (int e = 0; e < 16; e++) {
    int idxT = e * 256 + tid;
    int s = idxT >> 6, sp = idxT & 63;
    int src = sp * 64 + s;
    float st = 0.f;
#pragma unroll
    for (int c = 0; c < 4; c++) {
      STt[((size_t)c * 128 + bh) * 4096 + idxT] = f2bf(st);
      st = ws * st + SC[((size_t)c * 128 + bh) * 4096 + src];
    }
  }
}

// ---- attention output (MFMA, batched over chunks; 34KB LDS) -----------------
__global__ __launch_bounds__(256) void att_out_m(const u16* __restrict__ R,
                                                 const u16* __restrict__ K,
                                                 const u16* __restrict__ V,
                                                 const u16* __restrict__ STt,
                                                 const float* __restrict__ wb_tab,
                                                 const float* __restrict__ u_vec,
                                                 u16* __restrict__ xa) {
  const int bh = blockIdx.x;
  const int ti = blockIdx.y;
  const int c  = blockIdx.z;
  const int b = bh >> 5, h = bh & 31;
  const int tid = threadIdx.x, w = tid >> 6, lane = tid & 63;
  const int fr = lane & 15, fq = lane >> 4;
  const int t0 = ti * 64;
  const size_t chunkbase = (size_t)b * TT_ + (size_t)c * TCH;
  const u16* Rp = R + (chunkbase + t0) * C_ + h * 64;
  const u16* Kp = K + chunkbase * C_ + h * 64;
  const u16* Vp = V + chunkbase * C_ + h * 64;

  __shared__ alignas(16) u16 Rs[64 * 64];
  __shared__ alignas(16) u16 Ks[64 * 64];
  __shared__ alignas(16) u16 Vts[64 * 64];
  __shared__ alignas(16) u16 Xs[64 * 64];
  __shared__ float wbs[512];

#pragma unroll
  for (int it = 0; it < 2; it++) {
    int r = (tid >> 3) + it * 32;
    int cb = (tid & 7) * 16;
    uint4 d = *(const uint4*)((const char*)(Rp + (size_t)r * C_) + cb);
    int byte = (r * 128 + cb) ^ ((r & 7) << 4);
    *(uint4*)((char*)Rs + byte) = d;
  }
  const u16* stg = STt + ((size_t)c * 128 + bh) * 4096;
#pragma unroll
  for (int it = 0; it < 2; it++) {
    int s = (tid >> 3) + it * 32;
    int cb = (tid & 7) * 16;
    uint4 d = *(const uint4*)((const char*)(stg + (size_t)s * 64) + cb);
    int byte = (s * 128 + cb) ^ ((s & 7) << 4);
    *(uint4*)((char*)Xs + byte) = d;
  }
  wbs[tid] = wb_tab[h * TCH + tid];
  wbs[tid + 256] = wb_tab[h * TCH + tid + 256];
  const float uh = u_vec[h];
  __syncthreads();

  f32x4 pv[4];
#pragma unroll
  for (int n = 0; n < 4; n++) pv[n] = (f32x4){0.f, 0.f, 0.f, 0.f};
#pragma unroll
  for (int kk = 0; kk < 2; kk++) {
    int rbA = ((w * 16 + fr) * 128 + kk * 64 + fq * 16) ^ ((fr & 7) << 4);
    bf16x8 av = *(const bf16x8*)((char*)Rs + rbA);
#pragma unroll
    for (int n = 0; n < 4; n++) {
      int rbB = ((n * 16 + fr) * 128 + kk * 64 + fq * 16) ^ ((fr & 7) << 4);
      bf16x8 bv = *(const bf16x8*)((char*)Xs + rbB);
      pv[n] = __builtin_amdgcn_mfma_f32_16x16x32_bf16(av, bv, pv[n], 0, 0, 0);
    }
  }
#pragma unroll
  for (int n = 0; n < 4; n++)
#pragma unroll
    for (int j = 0; j < 4; j++) {
      int tg = t0 + w * 16 + fq * 4 + j;
      pv[n][j] *= wbs[tg];
    }

  for (int ub = 0; ub <= ti; ub++) {
    const int u0 = ub * 64;
    __syncthreads();
#pragma unroll
    for (int it = 0; it < 2; it++) {
      int r = (tid >> 3) + it * 32;
      int cb = (tid & 7) * 16;
      uint4 d = *(const uint4*)((const char*)(Kp + (size_t)(u0 + r) * C_) + cb);
      int byte = (r * 128 + cb) ^ ((r & 7) << 4);
      *(uint4*)((char*)Ks + byte) = d;
    }
#pragma unroll
    for (int it = 0; it < 2; it++) {
      int u = (tid >> 3) + it * 32;
      int s0 = (tid & 7) * 8;
      uint4 d = *(const uint4*)(Vp + (size_t)(u0 + u) * C_ + s0);
      const u16* ev = (const u16*)&d;
#pragma unroll
      for (int j = 0; j < 8; j++) {
        int s = s0 + j;
        int byte = (s * 128 + u * 2) ^ ((s & 7) << 4);
        *(u16*)((char*)Vts + byte) = ev[j];
      }
    }
    __syncthreads();
    f32x4 accA[4];
#pragma unroll
    for (int n = 0; n < 4; n++) accA[n] = (f32x4){0.f, 0.f, 0.f, 0.f};
#pragma unroll
    for (int kk = 0; kk < 2; kk++) {
      int rbA = ((w * 16 + fr) * 128 + kk * 64 + fq * 16) ^ ((fr & 7) << 4);
      bf16x8 av = *(const bf16x8*)((char*)Rs + rbA);
#pragma unroll
      for (int n = 0; n < 4; n++) {
        int rbB = ((n * 16 + fr) * 128 + kk * 64 + fq * 16) ^ ((fr & 7) << 4);
        bf16x8 bv = *(const bf16x8*)((char*)Ks + rbB);
        accA[n] = __builtin_amdgcn_mfma_f32_16x16x32_bf16(av, bv, accA[n], 0, 0, 0);
      }
    }
#pragma unroll
    for (int n = 0; n < 4; n++) {
#pragma unroll
      for (int j = 0; j < 4; j++) {
        int tl = w * 16 + fq * 4 + j;
        int tg = t0 + tl;
        int u = u0 + n * 16 + fr;
        int d = tg - u;
        float f = (d > 0) ? wbs[d - 1] : ((d == 0) ? uh : 0.f);
        int byte = (tl * 128 + (n * 16 + fr) * 2) ^ ((tl & 7) << 4);
        *(u16*)((char*)Xs + byte) = f2bf(accA[n][j] * f);
      }
    }
#pragma unroll
    for (int kk = 0; kk < 2; kk++) {
      int rbA = ((w * 16 + fr) * 128 + kk * 64 + fq * 16) ^ ((fr & 7) << 4);
      bf16x8 ap = *(const bf16x8*)((char*)Xs + rbA);
#pragma unroll
      for (int n = 0; n < 4; n++) {
        int rbB = ((n * 16 + fr) * 128 + kk * 64 + fq * 16) ^ ((fr & 7) << 4);
        bf16x8 vp = *(const bf16x8*)((char*)Vts + rbB);
        pv[n] = __builtin_amdgcn_mfma_f32_16x16x32_bf16(ap, vp, pv[n], 0, 0, 0);
      }
    }
  }
  u16* xout = xa + (chunkbase + t0) * C_ + h * 64;
#pragma unroll
  for (int n = 0; n < 4; n++)
#pragma unroll
    for (int j = 0; j < 4; j++) {
      int tl = w * 16 + fq * 4 + j;
      xout[(size_t)tl * C_ + n * 16 + fr] = f2bf(pv[n][j]);
    }
}

// ---- per-head groupnorm ------------------------------------------------------
__global__ __launch_bounds__(256) void gnorm(const u16* __restrict__ xa,
                                             const float* __restrict__ g,
                                             const float* __restrict__ b,
                                             u16* __restrict__ out) {
  const int row = blockIdx.x;
  const int lane = threadIdx.x & 63, wv = threadIdx.x >> 6;
  const u16* xp = xa + (size_t)row * C_;
  u16* op = out + (size_t)row * C_;
  for (int h = wv; h < 32; h += 4) {
    float v = bf2f(xp[h * 64 + lane]) * 0.125f;
    float s = v, s2 = v * v;
#pragma unroll
    for (int o = 32; o > 0; o >>= 1) { s += __shfl_down(s, o); s2 += __shfl_down(s2, o); }
    s = __shfl(s, 0); s2 = __shfl(s2, 0);
    float m = s * (1.f / 64.f), var = s2 * (1.f / 64.f) - m * m;
    float nv = (v - m) * rsqrtf(var + 1e-5f);
    op[h * 64 + lane] = f2bf(nv * g[h * 64 + lane] + b[h * 64 + lane]);
  }
}

// ---- launcher ---------------------------------------------------------------
extern "C" void kernel_launch(void* const* d_in, const int* in_sizes, int n_in,
                              void* d_out, int out_size, void* d_ws, size_t ws_size,
                              hipStream_t stream) {
  (void)in_sizes; (void)n_in; (void)out_size; (void)ws_size;
  const float* x    = (const float*)d_in[0];
  const float* ln1g = (const float*)d_in[1];
  const float* ln1b = (const float*)d_in[2];
  const float* ln2g = (const float*)d_in[3];
  const float* ln2b = (const float*)d_in[4];
  const float* amk  = (const float*)d_in[5];
  const float* amv  = (const float*)d_in[6];
  const float* amr  = (const float*)d_in[7];
  const float* tdec = (const float*)d_in[8];
  const float* tfaa = (const float*)d_in[9];
  const float* Wr   = (const float*)d_in[10];
  const float* Wk   = (const float*)d_in[11];
  const float* Wv   = (const float*)d_in[12];
  const float* Wo   = (const float*)d_in[13];
  const float* lnxg = (const float*)d_in[14];
  const float* lnxb = (const float*)d_in[15];
  const float* fmk  = (const float*)d_in[16];
  const float* fmr  = (const float*)d_in[17];
  const float* Wfk  = (const float*)d_in[18];
  const float* Wfr  = (const float*)d_in[19];
  const float* Wfv  = (const float*)d_in[20];

  char* ws = (char*)d_ws;
  const size_t MB = 1ull << 20;
  u16* WR  = (u16*)(ws + 0 * MB);
  u16* WK  = (u16*)(ws + 8 * MB);
  u16* WV  = (u16*)(ws + 16 * MB);
  u16* WO  = (u16*)(ws + 24 * MB);
  u16* WFR = (u16*)(ws + 32 * MB);
  u16* WFK = (u16*)(ws + 40 * MB);
  u16* WFV = (u16*)(ws + 68 * MB);
  u16* H1  = (u16*)(ws + 96 * MB);
  u16* XR  = (u16*)(ws + 128 * MB);
  u16* XK  = (u16*)(ws + 160 * MB);
  u16* XV  = (u16*)(ws + 192 * MB);
  float* WBT = (float*)(ws + 224 * MB);
  float* WKT = (float*)(ws + 224 * MB + 65536);
  float* WSP = (float*)(ws + 224 * MB + 131072);
  float* SCb = (float*)(ws + 0 * MB);
  u16* STTb  = (u16*)(ws + 8 * MB);
  u16* RB   = H1;
  u16* KB   = XR;
  u16* VB   = XK;
  u16* XA   = XV;
  u16* XAN  = H1;
  u16* H2   = XV;
  u16* XK2  = WR;
  u16* XR2  = H1;
  u16* SR   = XR;
  u16* KFH  = XK;                    // (4096, 7168) bf16 M-half = 56 MB (160-216)
  float* OUT = (float*)d_out;

  dim3 blk(256), gblk(512);
  wcvt_t<<<dim3(64, 64), blk, 0, stream>>>(Wr, WR, 2048, 2048, 0);
  wcvt_t<<<dim3(64, 64), blk, 0, stream>>>(Wk, WK, 2048, 2048, 0);
  wcvt_t<<<dim3(64, 64), blk, 0, stream>>>(Wv, WV, 2048, 2048, 0);
  wcvt_t<<<dim3(64, 64), blk, 0, stream>>>(Wo, WO, 2048, 2048, 0);
  wcvt_t<<<dim3(64, 64), blk, 0, stream>>>(Wfr, WFR, 2048, 2048, 0);
  wcvt_t<<<dim3(224, 64), blk, 0, stream>>>(Wfk, WFK, 2048, 7168, 0);
  wcvt_t<<<dim3(64, 224), blk, 0, stream>>>(Wfv, WFV, 7168, 2048, 0);

  // ---- attention branch ----
  ln_rows<<<8192, blk, 0, stream>>>(x, ln1g, ln1b, H1);
  mix3<<<8192, blk, 0, stream>>>(H1, amk, amv, amr, XK, XV, XR);
  gemm4<0><<<256, gblk, 0, stream>>>(XR, WR, RB, nullptr, 2048, 2048, 2048, 2048, 8);
  gemm4<0><<<256, gblk, 0, stream>>>(XK, WK, KB, nullptr, 2048, 2048, 2048, 2048, 8);
  gemm4<0><<<256, gblk, 0, stream>>>(XV, WV, VB, nullptr, 2048, 2048, 2048, 2048, 8);

  wtabs_k<<<32, 512, 0, stream>>>(tdec, WBT, WKT, WSP);
  kvsum_m<<<512, blk, 0, stream>>>(KB, VB, WKT, SCb);
  stcomb<<<128, blk, 0, stream>>>(SCb, STTb, WSP);
  att_out_m<<<dim3(128, 8, 4), blk, 0, stream>>>(RB, KB, VB, STTb, WBT, tfaa, XA);

  gnorm<<<8192, blk, 0, stream>>>(XA, lnxg, lnxb, XAN);
  gemm4<1><<<256, gblk, 0, stream>>>(XAN, WO, OUT, x, 2048, 2048, 2048, 2048, 8);

  // ---- FFN branch (M-split, round-14 validated structure) ----
  ln_rows<<<8192, blk, 0, stream>>>(OUT, ln2g, ln2b, H2);
  mix2<<<8192, blk, 0, stream>>>(H2, fmk, fmr, XK2, XR2);
  gemm4<3><<<256, gblk, 0, stream>>>(XR2, WFR, SR, nullptr, 2048, 2048, 2048, 2048, 8);

  for (int half = 0; half < 2; half++) {
    const u16* a_half = XK2 + (size_t)half * 4096 * 2048;
    gemm4<2><<<448, gblk, 0, stream>>>(a_half, WFK, KFH, nullptr,
                                       7168, 2048, 2048, 2048, 28);
    gemm3b<9><<<256, gblk, 0, stream>>>(KFH, WFV, OUT + (size_t)half * 4096 * 2048,
                                        SR + (size_t)half * 4096 * 2048,
                                        2048, 7168, 7168, 7168, 8);
  }
}

// Round 18
// 1202.846 us; speedup vs baseline: 1.0908x; 1.0402x over previous
//
#include <hip/hip_runtime.h>

#define B_   4
#define TT_  2048
#define C_   2048
#define H_   32
#define S_   64
#define DF_  7168
#define TCH  512
#define NCH  4

typedef unsigned short u16;
typedef __bf16 bf16x8 __attribute__((ext_vector_type(8)));
typedef float  f32x4  __attribute__((ext_vector_type(4)));

__device__ __forceinline__ u16 f2bf(float f) {
  unsigned u = __builtin_bit_cast(unsigned, f);
  u = u + 0x7FFFu + ((u >> 16) & 1u);
  return (u16)(u >> 16);
}
__device__ __forceinline__ float bf2f(u16 v) {
  unsigned u = ((unsigned)v) << 16;
  return __builtin_bit_cast(float, u);
}

#define GLOAD16(g, l) __builtin_amdgcn_global_load_lds( \
    (const __attribute__((address_space(1))) void*)(g), \
    (__attribute__((address_space(3))) void*)(l), 16, 0, 0)

__device__ __forceinline__ void vmcnt6() { asm volatile("s_waitcnt vmcnt(6)" ::: "memory"); }
__device__ __forceinline__ void vmcnt2() { asm volatile("s_waitcnt vmcnt(2)" ::: "memory"); }
__device__ __forceinline__ void vmcnt0() { asm volatile("s_waitcnt vmcnt(0)" ::: "memory"); }

// ---- weight convert+transpose ----------------------------------------------
__global__ __launch_bounds__(256) void wcvt_t(const float* __restrict__ W,
                                              u16* __restrict__ Wt, int K, int Nfull,
                                              int n0off) {
  __shared__ alignas(16) float tile[32][33];
  int nloc = blockIdx.x * 32, k0 = blockIdx.y * 32;
  int tx = threadIdx.x & 31, ty = threadIdx.x >> 5;
  for (int r = ty; r < 32; r += 8)
    tile[r][tx] = W[(size_t)(k0 + r) * Nfull + n0off + nloc + tx];
  __syncthreads();
  for (int r = ty; r < 32; r += 8)
    Wt[(size_t)(nloc + r) * K + k0 + tx] = f2bf(tile[tx][r]);
}

// ---- layernorm over C=2048, f32 in -> bf16 out ------------------------------
__global__ __launch_bounds__(256) void ln_rows(const float* __restrict__ x,
                                               const float* __restrict__ g,
                                               const float* __restrict__ b,
                                               u16* __restrict__ out) {
  const int row = blockIdx.x;
  const float* xr = x + (size_t)row * C_;
  float v[8]; float s = 0.f, s2 = 0.f;
#pragma unroll
  for (int i = 0; i < 8; i++) { v[i] = xr[threadIdx.x + i * 256]; s += v[i]; s2 += v[i] * v[i]; }
#pragma unroll
  for (int o = 32; o > 0; o >>= 1) { s += __shfl_down(s, o); s2 += __shfl_down(s2, o); }
  __shared__ float rs[4], rs2[4];
  int wid = threadIdx.x >> 6, lane = threadIdx.x & 63;
  if (lane == 0) { rs[wid] = s; rs2[wid] = s2; }
  __syncthreads();
  s = rs[0] + rs[1] + rs[2] + rs[3];
  s2 = rs2[0] + rs2[1] + rs2[2] + rs2[3];
  float m = s * (1.f / C_);
  float var = s2 * (1.f / C_) - m * m;
  float inv = rsqrtf(var + 1e-5f);
  u16* orow = out + (size_t)row * C_;
#pragma unroll
  for (int i = 0; i < 8; i++) {
    int c = threadIdx.x + i * 256;
    orow[c] = f2bf((v[i] - m) * inv * g[c] + b[c]);
  }
}

// ---- decay tables -----------------------------------------------------------
__global__ void wtabs_k(const float* __restrict__ td, float* __restrict__ wb_tab,
                        float* __restrict__ wk_tab, float* __restrict__ wspow) {
  int h = blockIdx.x, t = threadIdx.x;
  float w = expf(-expf(td[h]));
  wb_tab[h * TCH + t] = powf(w, (float)t);
  wk_tab[h * TCH + t] = powf(w, (float)(TCH - 1 - t));
  if (t == 0) wspow[h] = powf(w, (float)TCH);
}

// ---- time-shift mixes -------------------------------------------------------
__device__ __forceinline__ void mix_body(const u16* cur, const u16* prev, bool hasp,
                                         const float* mc, u16* dst) {
  ushort4 c0 = *(const ushort4*)cur;
  ushort4 c1 = *(const ushort4*)(cur + 4);
  ushort4 p0 = {0, 0, 0, 0}, p1 = {0, 0, 0, 0};
  if (hasp) { p0 = *(const ushort4*)prev; p1 = *(const ushort4*)(prev + 4); }
  float4 mA = *(const float4*)mc;
  float4 mB = *(const float4*)(mc + 4);
  ushort4 r0, r1;
  r0.x = f2bf(bf2f(c0.x) * mA.x + bf2f(p0.x) * (1.f - mA.x));
  r0.y = f2bf(bf2f(c0.y) * mA.y + bf2f(p0.y) * (1.f - mA.y));
  r0.z = f2bf(bf2f(c0.z) * mA.z + bf2f(p0.z) * (1.f - mA.z));
  r0.w = f2bf(bf2f(c0.w) * mA.w + bf2f(p0.w) * (1.f - mA.w));
  r1.x = f2bf(bf2f(c1.x) * mB.x + bf2f(p1.x) * (1.f - mB.x));
  r1.y = f2bf(bf2f(c1.y) * mB.y + bf2f(p1.y) * (1.f - mB.y));
  r1.z = f2bf(bf2f(c1.z) * mB.z + bf2f(p1.z) * (1.f - mB.z));
  r1.w = f2bf(bf2f(c1.w) * mB.w + bf2f(p1.w) * (1.f - mB.w));
  *(ushort4*)dst = r0;
  *(ushort4*)(dst + 4) = r1;
}

__global__ __launch_bounds__(256) void mix3(const u16* __restrict__ h,
                                            const float* __restrict__ mk,
                                            const float* __restrict__ mv,
                                            const float* __restrict__ mr,
                                            u16* __restrict__ xk, u16* __restrict__ xv,
                                            u16* __restrict__ xr) {
  size_t i8 = (size_t)blockIdx.x * 256 + threadIdx.x;
  size_t off = i8 * 8;
  int c0 = (int)(off & (C_ - 1));
  int row = (int)(i8 >> 8);
  bool hasp = (row & (TT_ - 1)) != 0;
  const u16* cur = h + off;
  const u16* prev = cur - C_;
  mix_body(cur, prev, hasp, mk + c0, xk + off);
  mix_body(cur, prev, hasp, mv + c0, xv + off);
  mix_body(cur, prev, hasp, mr + c0, xr + off);
}

__global__ __launch_bounds__(256) void mix2(const u16* __restrict__ h,
                                            const float* __restrict__ mk,
                                            const float* __restrict__ mr,
                                            u16* __restrict__ xk, u16* __restrict__ xr) {
  size_t i8 = (size_t)blockIdx.x * 256 + threadIdx.x;
  size_t off = i8 * 8;
  int c0 = (int)(off & (C_ - 1));
  int row = (int)(i8 >> 8);
  bool hasp = (row & (TT_ - 1)) != 0;
  const u16* cur = h + off;
  const u16* prev = cur - C_;
  mix_body(cur, prev, hasp, mk + c0, xk + off);
  mix_body(cur, prev, hasp, mr + c0, xr + off);
}

// ---- GEMM v6 (gemm4): BM=256, BN=256, BK=64, 512 thr / 8 waves (2M x 4N),
// wave tile 128x64 (acc[8][4]). 2 dbuf (128 KB). 4 phases, 2 BARRIERS/tile:
//  BARRIER1 after p1-stage vmcnt(2): cross-wave landing of A1,A3 (read in p2)
//  TRAILING barrier after p4: WAR guard + cross-wave landing of tile t+1's
//  B/A0/A2 (each wave's p4-end vmcnt(2) drained all but A1',A3').
// Staging order (B0,B1),(B2,B3),(A0,A2),(A1,A3); vmcnt(2) per phase; invariant:
// {A1',A3'} outstanding at tile boundary (validated round 14).
// EPI: 0 = bf16 store ; 1 = f32 out = acc + res ; 2 = bf16 relu(acc)^2 ; 3 = sigmoid
template <int EPI>
__global__ __launch_bounds__(512) void gemm4(const u16* __restrict__ A,
                                             const u16* __restrict__ Bt,
                                             void* __restrict__ Cv,
                                             const float* __restrict__ res,
                                             int N, int K, int lda, int ldb, int gy) {
  __shared__ alignas(16) u16 As[2][256 * 64];
  __shared__ alignas(16) u16 Bs[2][256 * 64];
  const int nwg = gridDim.x, qq = nwg >> 3;
  const int wg = (int)(blockIdx.x & 7) * qq + (int)(blockIdx.x >> 3);
  const int bx = wg / gy, by = wg % gy;
  const int tid = threadIdx.x, w = tid >> 6, lane = tid & 63;
  const int fr = lane & 15, fq = lane >> 4;
  const int m0 = bx * 256, n0 = by * 256;
  const int wm = (w >> 2) * 128;
  const int wn = (w & 3) * 64;
  const int rowS = tid >> 3;
  const int colS = ((tid & 7) * 8) ^ ((rowS & 7) << 3);
  const u16* Ag = A + (size_t)(m0 + rowS) * lda + colS;
  const u16* Bg = Bt + (size_t)(n0 + rowS) * ldb + colS;
  const int NT = K >> 6;

  f32x4 acc[8][4];
#pragma unroll
  for (int m = 0; m < 8; m++)
#pragma unroll
    for (int n = 0; n < 4; n++) acc[m][n] = (f32x4){0.f, 0.f, 0.f, 0.f};

#define STG_A4(p, k0, j) GLOAD16(Ag + (size_t)((j) * 64) * lda + (k0), \
    (char*)As[p] + (j) * 8192 + w * 1024)
#define STG_B4(p, k0, j) GLOAD16(Bg + (size_t)((j) * 64) * ldb + (k0), \
    (char*)Bs[p] + (j) * 8192 + w * 1024)
#define RD_A4(p, kk, r) (*(const bf16x8*)((char*)As[p] + \
    ((((r) * 128) + (kk) * 64 + fq * 16) ^ (((r) & 7) << 4))))
#define RD_B4(p, kk, r) (*(const bf16x8*)((char*)Bs[p] + \
    ((((r) * 128) + (kk) * 64 + fq * 16) ^ (((r) & 7) << 4))))

  // prologue: stage tile 0; issue A1,A3 LAST so vmcnt(2) leaves exactly them
  STG_B4(0, 0, 0); STG_B4(0, 0, 1); STG_B4(0, 0, 2); STG_B4(0, 0, 3);
  STG_A4(0, 0, 0); STG_A4(0, 0, 2); STG_A4(0, 0, 1); STG_A4(0, 0, 3);
  vmcnt2();
  __builtin_amdgcn_s_barrier();

  for (int t = 0; t < NT; t++) {
    const int p = t & 1;
    const bool st = (t + 1) < NT;
    const int k1 = (t + 1) << 6;
    bf16x8 av[4], bv[4];

    // ---- phase 1: kk0, M-half0 (reads guaranteed by t-1 trailing barrier) ----
#pragma unroll
    for (int i = 0; i < 4; i++) av[i] = RD_A4(p, 0, wm + i * 16 + fr);
#pragma unroll
    for (int n = 0; n < 4; n++) bv[n] = RD_B4(p, 0, wn + n * 16 + fr);
    if (st) { STG_B4(p ^ 1, k1, 0); STG_B4(p ^ 1, k1, 1); vmcnt2(); } else vmcnt0();
    __builtin_amdgcn_s_barrier();   // BARRIER1: A1,A3 landed across waves
    __builtin_amdgcn_s_setprio(1);
#pragma unroll
    for (int i = 0; i < 4; i++)
#pragma unroll
      for (int n = 0; n < 4; n++)
        acc[i][n] = __builtin_amdgcn_mfma_f32_16x16x32_bf16(av[i], bv[n], acc[i][n], 0, 0, 0);
    __builtin_amdgcn_s_setprio(0);

    // ---- phase 2: kk0, M-half1 (A1,A3 covered by BARRIER1; reuse bv) ----
#pragma unroll
    for (int i = 0; i < 4; i++) av[i] = RD_A4(p, 0, wm + 64 + i * 16 + fr);
    if (st) { STG_B4(p ^ 1, k1, 2); STG_B4(p ^ 1, k1, 3); vmcnt2(); }
    __builtin_amdgcn_s_setprio(1);
#pragma unroll
    for (int i = 0; i < 4; i++)
#pragma unroll
      for (int n = 0; n < 4; n++)
        acc[4 + i][n] = __builtin_amdgcn_mfma_f32_16x16x32_bf16(av[i], bv[n], acc[4 + i][n], 0, 0, 0);
    __builtin_amdgcn_s_setprio(0);

    // ---- phase 3: kk1, M-half0 ----
#pragma unroll
    for (int i = 0; i < 4; i++) av[i] = RD_A4(p, 1, wm + i * 16 + fr);
#pragma unroll
    for (int n = 0; n < 4; n++) bv[n] = RD_B4(p, 1, wn + n * 16 + fr);
    if (st) { STG_A4(p ^ 1, k1, 0); STG_A4(p ^ 1, k1, 2); vmcnt2(); }
    __builtin_amdgcn_s_setprio(1);
#pragma unroll
    for (int i = 0; i < 4; i++)
#pragma unroll
      for (int n = 0; n < 4; n++)
        acc[i][n] = __builtin_amdgcn_mfma_f32_16x16x32_bf16(av[i], bv[n], acc[i][n], 0, 0, 0);
    __builtin_amdgcn_s_setprio(0);

    // ---- phase 4: kk1, M-half1 (reuse bv) ----
#pragma unroll
    for (int i = 0; i < 4; i++) av[i] = RD_A4(p, 1, wm + 64 + i * 16 + fr);
    if (st) { STG_A4(p ^ 1, k1, 1); STG_A4(p ^ 1, k1, 3); vmcnt2(); }
    __builtin_amdgcn_s_setprio(1);
#pragma unroll
    for (int i = 0; i < 4; i++)
#pragma unroll
      for (int n = 0; n < 4; n++)
        acc[4 + i][n] = __builtin_amdgcn_mfma_f32_16x16x32_bf16(av[i], bv[n], acc[4 + i][n], 0, 0, 0);
    __builtin_amdgcn_s_setprio(0);
    __builtin_amdgcn_s_barrier();   // TRAILING: WAR + cross-wave landing of t+1 data
  }
#undef STG_A4
#undef STG_B4
#undef RD_A4
#undef RD_B4

#pragma unroll
  for (int m = 0; m < 8; m++)
#pragma unroll
    for (int n = 0; n < 4; n++)
#pragma unroll
      for (int j = 0; j < 4; j++) {
        int row = m0 + wm + m * 16 + fq * 4 + j;
        int col = n0 + wn + n * 16 + fr;
        size_t idx = (size_t)row * N + col;
        float v = acc[m][n][j];
        if (EPI == 0) ((u16*)Cv)[idx] = f2bf(v);
        else if (EPI == 1) ((float*)Cv)[idx] = v + res[idx];
        else if (EPI == 2) { float r = v > 0.f ? v : 0.f; ((u16*)Cv)[idx] = f2bf(r * r); }
        else ((u16*)Cv)[idx] = f2bf(1.f / (1.f + expf(-v)));
      }
}

// ---- gemm3b: BM=128, BN=256, 3-buffer ring (depth-2), 2 phases x 16 MFMA,
// ONE barrier per tile: tile-t data landed across waves at t-1's barrier
// (each wave's t-1 vmcnt(6) drained t's 6 loads); staging into b2 (buffer
// read at tile t-1) is WAR-safe because any wave entering tile t passed
// t-1's barrier, after all waves' t-1 reads completed. A fast wave at t+1
// stages into buf[t%3] only after ALL waves reached t's barrier (reads done).
// EPI: 9 = f32 out = out + bf16(sr)*acc
template <int EPI>
__global__ __launch_bounds__(512) void gemm3b(const u16* __restrict__ A,
                                              const u16* __restrict__ Bt,
                                              void* __restrict__ Cv,
                                              const u16* __restrict__ srp,
                                              int N, int K, int lda, int ldb, int gy) {
  __shared__ alignas(16) char smem[3 * 49152];
  const int nwg = gridDim.x, qq = nwg >> 3;
  const int wg = (int)(blockIdx.x & 7) * qq + (int)(blockIdx.x >> 3);
  const int bx = wg / gy, by = wg % gy;
  const int tid = threadIdx.x, w = tid >> 6, lane = tid & 63;
  const int fr = lane & 15, fq = lane >> 4;
  const int m0 = bx * 128, n0 = by * 256;
  const int wm = (w >> 2) * 64, wn = (w & 3) * 64;
  const int rowS = tid >> 3;
  const int colS = ((tid & 7) * 8) ^ ((rowS & 7) << 3);
  const u16* Ag = A + (size_t)(m0 + rowS) * lda + colS;
  const u16* Bg = Bt + (size_t)(n0 + rowS) * ldb + colS;
  const int NT = K >> 6;

  f32x4 acc[4][4];
#pragma unroll
  for (int m = 0; m < 4; m++)
#pragma unroll
    for (int n = 0; n < 4; n++) acc[m][n] = (f32x4){0.f, 0.f, 0.f, 0.f};

#define STG_A(buf, k0, j) GLOAD16(Ag + (size_t)((j) * 64) * lda + (k0), \
    smem + (buf) * 49152 + (j) * 8192 + w * 1024)
#define STG_B(buf, k0, j) GLOAD16(Bg + (size_t)((j) * 64) * ldb + (k0), \
    smem + (buf) * 49152 + 16384 + (j) * 8192 + w * 1024)
#define RD_A(buf, kk, m) (*(const bf16x8*)(smem + (buf) * 49152 + \
    ((((wm + (m) * 16 + fr) * 128) + (kk) * 64 + fq * 16) ^ (((wm + (m) * 16 + fr) & 7) << 4))))
#define RD_B(buf, kk, n) (*(const bf16x8*)(smem + (buf) * 49152 + 16384 + \
    ((((wn + (n) * 16 + fr) * 128) + (kk) * 64 + fq * 16) ^ (((wn + (n) * 16 + fr) & 7) << 4))))

  // prologue: stage tiles 0 and 1 (6 loads each); wait tile 0 only
  STG_A(0, 0, 0); STG_A(0, 0, 1);
  STG_B(0, 0, 0); STG_B(0, 0, 1); STG_B(0, 0, 2); STG_B(0, 0, 3);
  STG_A(1, 64, 0); STG_A(1, 64, 1);
  STG_B(1, 64, 0); STG_B(1, 64, 1); STG_B(1, 64, 2); STG_B(1, 64, 3);
  vmcnt6();
  __builtin_amdgcn_s_barrier();

  int bufc = 0;
  for (int t = 0; t < NT; t++) {
    int b2 = bufc + 2; if (b2 >= 3) b2 -= 3;
    const bool st = (t + 2) < NT;
    const int k2 = (t + 2) << 6;
    bf16x8 av[4], bv[4];

    // ---- phase 1: kk0, 16 MFMA ----
#pragma unroll
    for (int m = 0; m < 4; m++) av[m] = RD_A(bufc, 0, m);
#pragma unroll
    for (int n = 0; n < 4; n++) bv[n] = RD_B(bufc, 0, n);
    if (st) { STG_A(b2, k2, 0); STG_A(b2, k2, 1); STG_B(b2, k2, 0); }
    __builtin_amdgcn_s_setprio(1);
#pragma unroll
    for (int m = 0; m < 4; m++)
#pragma unroll
      for (int n = 0; n < 4; n++)
        acc[m][n] = __builtin_amdgcn_mfma_f32_16x16x32_bf16(av[m], bv[n], acc[m][n], 0, 0, 0);
    __builtin_amdgcn_s_setprio(0);

    // ---- phase 2: kk1, 16 MFMA ----
#pragma unroll
    for (int m = 0; m < 4; m++) av[m] = RD_A(bufc, 1, m);
#pragma unroll
    for (int n = 0; n < 4; n++) bv[n] = RD_B(bufc, 1, n);
    if (st) { STG_B(b2, k2, 1); STG_B(b2, k2, 2); STG_B(b2, k2, 3); }
    if (st) vmcnt6(); else vmcnt0();  // drain tile t+1's 6 loads; keep t+2's
    __builtin_amdgcn_s_setprio(1);
#pragma unroll
    for (int m = 0; m < 4; m++)
#pragma unroll
      for (int n = 0; n < 4; n++)
        acc[m][n] = __builtin_amdgcn_mfma_f32_16x16x32_bf16(av[m], bv[n], acc[m][n], 0, 0, 0);
    __builtin_amdgcn_s_setprio(0);
    __builtin_amdgcn_s_barrier();     // single per-tile barrier

    bufc = bufc + 1 == 3 ? 0 : bufc + 1;
  }
#undef STG_A
#undef STG_B
#undef RD_A
#undef RD_B

#pragma unroll
  for (int m = 0; m < 4; m++)
#pragma unroll
    for (int n = 0; n < 4; n++)
#pragma unroll
      for (int j = 0; j < 4; j++) {
        int row = m0 + wm + m * 16 + fq * 4 + j;
        int col = n0 + wn + n * 16 + fr;
        size_t idx = (size_t)row * N + col;
        float v = acc[m][n][j];
        if (EPI == 9) {
          float pvv = ((float*)Cv)[idx];
          ((float*)Cv)[idx] = pvv + bf2f(srp[idx]) * v;
        } else {
          ((u16*)Cv)[idx] = f2bf(v);
        }
      }
}

// ---- kvsum: per-chunk S_c[s][sv] = sum_t wk[t]*K[t][s]*V[t][sv]  (MFMA) -----
__global__ __launch_bounds__(256) void kvsum_m(const u16* __restrict__ K,
                                               const u16* __restrict__ V,
                                               const float* __restrict__ wk_tab,
                                               float* __restrict__ SC) {
  const int bh = blockIdx.x & 127, c = blockIdx.x >> 7;
  const int b = bh >> 5, h = bh & 31;
  const int tid = threadIdx.x, w = tid >> 6, lane = tid & 63;
  const int fr = lane & 15, fq = lane >> 4;
  const size_t chunkbase = (size_t)b * TT_ + (size_t)c * TCH;
  const u16* Kp = K + chunkbase * C_ + h * 64;
  const u16* Vp = V + chunkbase * C_ + h * 64;
  __shared__ alignas(16) u16 Kts[64 * 128];
  __shared__ alignas(16) u16 Vts[64 * 128];
  f32x4 acc[4];
#pragma unroll
  for (int n = 0; n < 4; n++) acc[n] = (f32x4){0.f, 0.f, 0.f, 0.f};

  for (int tb = 0; tb < 4; tb++) {
    __syncthreads();
    const int u = tid >> 1;
    const int tg = tb * 128 + u;
    const float wkv = wk_tab[h * TCH + tg];
#pragma unroll
    for (int i = 0; i < 4; i++) {
      int s0 = (tid & 1) * 32 + i * 8;
      uint4 dK = *(const uint4*)(Kp + (size_t)tg * C_ + s0);
      uint4 dV = *(const uint4*)(Vp + (size_t)tg * C_ + s0);
      const u16* ek = (const u16*)&dK;
      const u16* ev = (const u16*)&dV;
#pragma unroll
      for (int j = 0; j < 8; j++) {
        int s = s0 + j;
        int byte = s * 256 + u * 2;
        byte ^= (s & 7) << 4;
        *(u16*)((char*)Kts + byte) = f2bf(bf2f(ek[j]) * wkv);
        *(u16*)((char*)Vts + byte) = ev[j];
      }
    }
    __syncthreads();
#pragma unroll
    for (int kk = 0; kk < 4; kk++) {
      int rbyteA = (w * 16 + fr) * 256 + kk * 64 + fq * 16;
      rbyteA ^= (fr & 7) << 4;
      bf16x8 av = *(const bf16x8*)((char*)Kts + rbyteA);
#pragma unroll
      for (int n = 0; n < 4; n++) {
        int rbyteB = (n * 16 + fr) * 256 + kk * 64 + fq * 16;
        rbyteB ^= (fr & 7) << 4;
        bf16x8 bv = *(const bf16x8*)((char*)Vts + rbyteB);
        acc[n] = __builtin_amdgcn_mfma_f32_16x16x32_bf16(av, bv, acc[n], 0, 0, 0);
      }
    }
  }
  float* out = SC + ((size_t)c * 128 + bh) * 4096;
#pragma unroll
  for (int n = 0; n < 4; n++)
#pragma unroll
    for (int j = 0; j < 4; j++) {
      int srow = w * 16 + fq * 4 + j;
      int scol = n * 16 + fr;
      out[srow * 64 + scol] = acc[n][j];
    }
}

// ---- state combine: STt[c][s][sp] = bf16( sum_{j<c} ws^(c-1-j) SC[j][sp][s] )
__global__ __launch_bounds__(256) void stcomb(const float* __restrict__ SC,
                                              u16* __restrict__ STt,
                                              const float* __restrict__ wspow) {
  const int bh = blockIdx.x;
  const float ws = wspow[bh & 31];
  const int tid = threadIdx.x;
#pragma unroll
  for (int e = 0; e < 16; e++) {
    int idxT = e * 256 + tid;
    int s = idxT >> 6, sp = idxT & 63;
    int src = sp * 64 + s;
    float st = 0.f;
#pragma unroll
    for (int c = 0; c < 4; c++) {
      STt[((size_t)c * 128 + bh) * 4096 + idxT] = f2bf(st);
      st = ws * st + SC[((size_t)c * 128 + bh) * 4096 + src];
    }
  }
}

// ---- attention output (MFMA, batched over chunks; 34KB LDS) -----------------
__global__ __launch_bounds__(256) void att_out_m(const u16* __restrict__ R,
                                                 const u16* __restrict__ K,
                                                 const u16* __restrict__ V,
                                                 const u16* __restrict__ STt,
                                                 const float* __restrict__ wb_tab,
                                                 const float* __restrict__ u_vec,
                                                 u16* __restrict__ xa) {
  const int bh = blockIdx.x;
  const int ti = blockIdx.y;
  const int c  = blockIdx.z;
  const int b = bh >> 5, h = bh & 31;
  const int tid = threadIdx.x, w = tid >> 6, lane = tid & 63;
  const int fr = lane & 15, fq = lane >> 4;
  const int t0 = ti * 64;
  const size_t chunkbase = (size_t)b * TT_ + (size_t)c * TCH;
  const u16* Rp = R + (chunkbase + t0) * C_ + h * 64;
  const u16* Kp = K + chunkbase * C_ + h * 64;
  const u16* Vp = V + chunkbase * C_ + h * 64;

  __shared__ alignas(16) u16 Rs[64 * 64];
  __shared__ alignas(16) u16 Ks[64 * 64];
  __shared__ alignas(16) u16 Vts[64 * 64];
  __shared__ alignas(16) u16 Xs[64 * 64];
  __shared__ float wbs[512];

#pragma unroll
  for (int it = 0; it < 2; it++) {
    int r = (tid >> 3) + it * 32;
    int cb = (tid & 7) * 16;
    uint4 d = *(const uint4*)((const char*)(Rp + (size_t)r * C_) + cb);
    int byte = (r * 128 + cb) ^ ((r & 7) << 4);
    *(uint4*)((char*)Rs + byte) = d;
  }
  const u16* stg = STt + ((size_t)c * 128 + bh) * 4096;
#pragma unroll
  for (int it = 0; it < 2; it++) {
    int s = (tid >> 3) + it * 32;
    int cb = (tid & 7) * 16;
    uint4 d = *(const uint4*)((const char*)(stg + (size_t)s * 64) + cb);
    int byte = (s * 128 + cb) ^ ((s & 7) << 4);
    *(uint4*)((char*)Xs + byte) = d;
  }
  wbs[tid] = wb_tab[h * TCH + tid];
  wbs[tid + 256] = wb_tab[h * TCH + tid + 256];
  const float uh = u_vec[h];
  __syncthreads();

  f32x4 pv[4];
#pragma unroll
  for (int n = 0; n < 4; n++) pv[n] = (f32x4){0.f, 0.f, 0.f, 0.f};
#pragma unroll
  for (int kk = 0; kk < 2; kk++) {
    int rbA = ((w * 16 + fr) * 128 + kk * 64 + fq * 16) ^ ((fr & 7) << 4);
    bf16x8 av = *(const bf16x8*)((char*)Rs + rbA);
#pragma unroll
    for (int n = 0; n < 4; n++) {
      int rbB = ((n * 16 + fr) * 128 + kk * 64 + fq * 16) ^ ((fr & 7) << 4);
      bf16x8 bv = *(const bf16x8*)((char*)Xs + rbB);
      pv[n] = __builtin_amdgcn_mfma_f32_16x16x32_bf16(av, bv, pv[n], 0, 0, 0);
    }
  }
#pragma unroll
  for (int n = 0; n < 4; n++)
#pragma unroll
    for (int j = 0; j < 4; j++) {
      int tg = t0 + w * 16 + fq * 4 + j;
      pv[n][j] *= wbs[tg];
    }

  for (int ub = 0; ub <= ti; ub++) {
    const int u0 = ub * 64;
    __syncthreads();
#pragma unroll
    for (int it = 0; it < 2; it++) {
      int r = (tid >> 3) + it * 32;
      int cb = (tid & 7) * 16;
      uint4 d = *(const uint4*)((const char*)(Kp + (size_t)(u0 + r) * C_) + cb);
      int byte = (r * 128 + cb) ^ ((r & 7) << 4);
      *(uint4*)((char*)Ks + byte) = d;
    }
#pragma unroll
    for (int it = 0; it < 2; it++) {
      int u = (tid >> 3) + it * 32;
      int s0 = (tid & 7) * 8;
      uint4 d = *(const uint4*)(Vp + (size_t)(u0 + u) * C_ + s0);
      const u16* ev = (const u16*)&d;
#pragma unroll
      for (int j = 0; j < 8; j++) {
        int s = s0 + j;
        int byte = (s * 128 + u * 2) ^ ((s & 7) << 4);
        *(u16*)((char*)Vts + byte) = ev[j];
      }
    }
    __syncthreads();
    f32x4 accA[4];
#pragma unroll
    for (int n = 0; n < 4; n++) accA[n] = (f32x4){0.f, 0.f, 0.f, 0.f};
#pragma unroll
    for (int kk = 0; kk < 2; kk++) {
      int rbA = ((w * 16 + fr) * 128 + kk * 64 + fq * 16) ^ ((fr & 7) << 4);
      bf16x8 av = *(const bf16x8*)((char*)Rs + rbA);
#pragma unroll
      for (int n = 0; n < 4; n++) {
        int rbB = ((n * 16 + fr) * 128 + kk * 64 + fq * 16) ^ ((fr & 7) << 4);
        bf16x8 bv = *(const bf16x8*)((char*)Ks + rbB);
        accA[n] = __builtin_amdgcn_mfma_f32_16x16x32_bf16(av, bv, accA[n], 0, 0, 0);
      }
    }
#pragma unroll
    for (int n = 0; n < 4; n++) {
#pragma unroll
      for (int j = 0; j < 4; j++) {
        int tl = w * 16 + fq * 4 + j;
        int tg = t0 + tl;
        int u = u0 + n * 16 + fr;
        int d = tg - u;
        float f = (d > 0) ? wbs[d - 1] : ((d == 0) ? uh : 0.f);
        int byte = (tl * 128 + (n * 16 + fr) * 2) ^ ((tl & 7) << 4);
        *(u16*)((char*)Xs + byte) = f2bf(accA[n][j] * f);
      }
    }
#pragma unroll
    for (int kk = 0; kk < 2; kk++) {
      int rbA = ((w * 16 + fr) * 128 + kk * 64 + fq * 16) ^ ((fr & 7) << 4);
      bf16x8 ap = *(const bf16x8*)((char*)Xs + rbA);
#pragma unroll
      for (int n = 0; n < 4; n++) {
        int rbB = ((n * 16 + fr) * 128 + kk * 64 + fq * 16) ^ ((fr & 7) << 4);
        bf16x8 vp = *(const bf16x8*)((char*)Vts + rbB);
        pv[n] = __builtin_amdgcn_mfma_f32_16x16x32_bf16(ap, vp, pv[n], 0, 0, 0);
      }
    }
  }
  u16* xout = xa + (chunkbase + t0) * C_ + h * 64;
#pragma unroll
  for (int n = 0; n < 4; n++)
#pragma unroll
    for (int j = 0; j < 4; j++) {
      int tl = w * 16 + fq * 4 + j;
      xout[(size_t)tl * C_ + n * 16 + fr] = f2bf(pv[n][j]);
    }
}

// ---- per-head groupnorm ------------------------------------------------------
__global__ __launch_bounds__(256) void gnorm(const u16* __restrict__ xa,
                                             const float* __restrict__ g,
                                             const float* __restrict__ b,
                                             u16* __restrict__ out) {
  const int row = blockIdx.x;
  const int lane = threadIdx.x & 63, wv = threadIdx.x >> 6;
  const u16* xp = xa + (size_t)row * C_;
  u16* op = out + (size_t)row * C_;
  for (int h = wv; h < 32; h += 4) {
    float v = bf2f(xp[h * 64 + lane]) * 0.125f;
    float s = v, s2 = v * v;
#pragma unroll
    for (int o = 32; o > 0; o >>= 1) { s += __shfl_down(s, o); s2 += __shfl_down(s2, o); }
    s = __shfl(s, 0); s2 = __shfl(s2, 0);
    float m = s * (1.f / 64.f), var = s2 * (1.f / 64.f) - m * m;
    float nv = (v - m) * rsqrtf(var + 1e-5f);
    op[h * 64 + lane] = f2bf(nv * g[h * 64 + lane] + b[h * 64 + lane]);
  }
}

// ---- launcher ---------------------------------------------------------------
extern "C" void kernel_launch(void* const* d_in, const int* in_sizes, int n_in,
                              void* d_out, int out_size, void* d_ws, size_t ws_size,
                              hipStream_t stream) {
  (void)in_sizes; (void)n_in; (void)out_size; (void)ws_size;
  const float* x    = (const float*)d_in[0];
  const float* ln1g = (const float*)d_in[1];
  const float* ln1b = (const float*)d_in[2];
  const float* ln2g = (const float*)d_in[3];
  const float* ln2b = (const float*)d_in[4];
  const float* amk  = (const float*)d_in[5];
  const float* amv  = (const float*)d_in[6];
  const float* amr  = (const float*)d_in[7];
  const float* tdec = (const float*)d_in[8];
  const float* tfaa = (const float*)d_in[9];
  const float* Wr   = (const float*)d_in[10];
  const float* Wk   = (const float*)d_in[11];
  const float* Wv   = (const float*)d_in[12];
  const float* Wo   = (const float*)d_in[13];
  const float* lnxg = (const float*)d_in[14];
  const float* lnxb = (const float*)d_in[15];
  const float* fmk  = (const float*)d_in[16];
  const float* fmr  = (const float*)d_in[17];
  const float* Wfk  = (const float*)d_in[18];
  const float* Wfr  = (const float*)d_in[19];
  const float* Wfv  = (const float*)d_in[20];

  char* ws = (char*)d_ws;
  const size_t MB = 1ull << 20;
  u16* WR  = (u16*)(ws + 0 * MB);
  u16* WK  = (u16*)(ws + 8 * MB);
  u16* WV  = (u16*)(ws + 16 * MB);
  u16* WO  = (u16*)(ws + 24 * MB);
  u16* WFR = (u16*)(ws + 32 * MB);
  u16* WFK = (u16*)(ws + 40 * MB);
  u16* WFV = (u16*)(ws + 68 * MB);
  u16* H1  = (u16*)(ws + 96 * MB);
  u16* XR  = (u16*)(ws + 128 * MB);
  u16* XK  = (u16*)(ws + 160 * MB);
  u16* XV  = (u16*)(ws + 192 * MB);
  float* WBT = (float*)(ws + 224 * MB);
  float* WKT = (float*)(ws + 224 * MB + 65536);
  float* WSP = (float*)(ws + 224 * MB + 131072);
  float* SCb = (float*)(ws + 0 * MB);
  u16* STTb  = (u16*)(ws + 8 * MB);
  u16* RB   = H1;
  u16* KB   = XR;
  u16* VB   = XK;
  u16* XA   = XV;
  u16* XAN  = H1;
  u16* H2   = XV;
  u16* XK2  = WR;
  u16* XR2  = H1;
  u16* SR   = XR;
  u16* KFH  = XK;                    // (4096, 7168) bf16 M-half = 56 MB (160-216)
  float* OUT = (float*)d_out;

  dim3 blk(256), gblk(512);
  wcvt_t<<<dim3(64, 64), blk, 0, stream>>>(Wr, WR, 2048, 2048, 0);
  wcvt_t<<<dim3(64, 64), blk, 0, stream>>>(Wk, WK, 2048, 2048, 0);
  wcvt_t<<<dim3(64, 64), blk, 0, stream>>>(Wv, WV, 2048, 2048, 0);
  wcvt_t<<<dim3(64, 64), blk, 0, stream>>>(Wo, WO, 2048, 2048, 0);
  wcvt_t<<<dim3(64, 64), blk, 0, stream>>>(Wfr, WFR, 2048, 2048, 0);
  wcvt_t<<<dim3(224, 64), blk, 0, stream>>>(Wfk, WFK, 2048, 7168, 0);
  wcvt_t<<<dim3(64, 224), blk, 0, stream>>>(Wfv, WFV, 7168, 2048, 0);

  // ---- attention branch ----
  ln_rows<<<8192, blk, 0, stream>>>(x, ln1g, ln1b, H1);
  mix3<<<8192, blk, 0, stream>>>(H1, amk, amv, amr, XK, XV, XR);
  gemm4<0><<<256, gblk, 0, stream>>>(XR, WR, RB, nullptr, 2048, 2048, 2048, 2048, 8);
  gemm4<0><<<256, gblk, 0, stream>>>(XK, WK, KB, nullptr, 2048, 2048, 2048, 2048, 8);
  gemm4<0><<<256, gblk, 0, stream>>>(XV, WV, VB, nullptr, 2048, 2048, 2048, 2048, 8);

  wtabs_k<<<32, 512, 0, stream>>>(tdec, WBT, WKT, WSP);
  kvsum_m<<<512, blk, 0, stream>>>(KB, VB, WKT, SCb);
  stcomb<<<128, blk, 0, stream>>>(SCb, STTb, WSP);
  att_out_m<<<dim3(128, 8, 4), blk, 0, stream>>>(RB, KB, VB, STTb, WBT, tfaa, XA);

  gnorm<<<8192, blk, 0, stream>>>(XA, lnxg, lnxb, XAN);
  gemm4<1><<<256, gblk, 0, stream>>>(XAN, WO, OUT, x, 2048, 2048, 2048, 2048, 8);

  // ---- FFN branch (M-split) ----
  ln_rows<<<8192, blk, 0, stream>>>(OUT, ln2g, ln2b, H2);
  mix2<<<8192, blk, 0, stream>>>(H2, fmk, fmr, XK2, XR2);
  gemm4<3><<<256, gblk, 0, stream>>>(XR2, WFR, SR, nullptr, 2048, 2048, 2048, 2048, 8);

  for (int half = 0; half < 2; half++) {
    const u16* a_half = XK2 + (size_t)half * 4096 * 2048;
    gemm4<2><<<448, gblk, 0, stream>>>(a_half, WFK, KFH, nullptr,
                                       7168, 2048, 2048, 2048, 28);
    gemm3b<9><<<256, gblk, 0, stream>>>(KFH, WFV, OUT + (size_t)half * 4096 * 2048,
                                        SR + (size_t)half * 4096 * 2048,
                                        2048, 7168, 7168, 7168, 8);
  }
}